// Round 10
// baseline (545.154 us; speedup 1.0000x reference)
//
#include <hip/hip_runtime.h>
#include <hip/hip_bf16.h>

typedef unsigned long long ull;

// ---------------- problem constants ----------------
constexpr int BATCH = 8;
constexpr int NA    = 261888;
constexpr int KSEL  = 6000;          // PRE_NMS_LIMIT
constexpr int PROP  = 1000;          // PROPOSAL_COUNT
constexpr int CAP   = 8192;          // candidate capacity
constexpr int NBINS = 8192;          // histogram bins
constexpr int HB    = 16;            // private histogram blocks per batch
constexpr int NB    = (KSEL + 63) / 64;   // 94 mask words per row
constexpr int NWP   = 96;            // padded words per row (96*8 = 768B rows)
constexpr int NBLK  = (KSEL + 63) / 64;   // 94 row-blocks

// workspace layout (bytes). keys/rank/hist all live in the (later) mask region,
// at non-overlapping offsets; all die before mask_kernel writes.
constexpr size_t OFF_CNT   = 0;                       // 8*16*4 = 512
constexpr size_t OFF_TSEL  = 512;                     // 32
constexpr size_t OFF_BOXES = 544;                     // 8*6000*16 = 768000
constexpr size_t OFF_MASK  = 769024;                  // 8*6000*96*8 = 36864000
constexpr size_t OFF_KEYS  = OFF_MASK;                // 8*8192*8 = 524288
constexpr size_t OFF_RANK  = OFF_MASK + 524288;       // 8*8192*4 = 262144
constexpr size_t OFF_HIST  = OFF_MASK + 2097152;      // 4MB
// total = 37,633,024 B

__device__ __forceinline__ int score_bin(float s) {
  int b = (int)(s * (float)NBINS);
  if (b < 0) b = 0;
  if (b > NBINS - 1) b = NBINS - 1;
  return b;
}

// ---------------- 1. histogram (private per-block copies, no global atomics) ----------------
__global__ __launch_bounds__(256) void hist_kernel(const float2* __restrict__ probs,
                                                   unsigned int* __restrict__ hist) {
  __shared__ unsigned int lh[NBINS];
  for (int i = threadIdx.x; i < NBINS; i += 256) lh[i] = 0u;
  __syncthreads();
  int b = blockIdx.y;
  const float2* p = probs + (size_t)b * NA;
  for (int a = blockIdx.x * 256 + threadIdx.x; a < NA; a += HB * 256) {
    atomicAdd(&lh[score_bin(p[a].y)], 1u);
  }
  __syncthreads();
  unsigned int* gh = hist + ((size_t)b * HB + blockIdx.x) * NBINS;
  for (int i = threadIdx.x; i < NBINS; i += 256) gh[i] = lh[i];
}

// ---------------- 2. threshold bin select ----------------
__global__ __launch_bounds__(256) void thresh_kernel(const unsigned int* __restrict__ hist,
                                                     int* __restrict__ tsel) {
  constexpr int GR = NBINS / 256; // 32 bins per thread
  __shared__ unsigned int ch[NBINS];
  __shared__ unsigned int gsum[256];
  int b = blockIdx.x;
  const unsigned int* h = hist + (size_t)b * HB * NBINS;
  for (int bin = threadIdx.x; bin < NBINS; bin += 256) {
    unsigned int s = 0;
    for (int k = 0; k < HB; ++k) s += h[(size_t)k * NBINS + bin];
    ch[bin] = s;
  }
  __syncthreads();
  unsigned int s = 0;
  int g0 = threadIdx.x * GR;
  for (int i = 0; i < GR; ++i) s += ch[g0 + i];
  gsum[threadIdx.x] = s;
  __syncthreads();
  if (threadIdx.x == 0) {
    unsigned int acc = 0;
    int g = 255;
    for (; g > 0; --g) {
      if (acc + gsum[g] >= (unsigned)KSEL) break;
      acc += gsum[g];
    }
    int t = g * GR;
    for (int bin = g * GR + GR - 1; bin >= g * GR; --bin) {
      acc += ch[bin];
      if (acc >= (unsigned)KSEL) { t = bin; break; }
    }
    tsel[b] = t;
  }
}

// ---------------- 3. compact candidates (block-aggregated, 1 global atomic/block) ----------------
__global__ __launch_bounds__(256) void compact_kernel(const float2* __restrict__ probs,
                                                      const int* __restrict__ tsel,
                                                      int* __restrict__ cnt,
                                                      ull* __restrict__ keys) {
  __shared__ int lcnt, lbase;
  __shared__ ull lbuf[2048]; // block covers <=2048 anchors
  int b = blockIdx.y;
  int t = tsel[b];
  if (threadIdx.x == 0) lcnt = 0;
  __syncthreads();
  const float2* p = probs + (size_t)b * NA;
  for (int a = blockIdx.x * blockDim.x + threadIdx.x; a < NA; a += gridDim.x * blockDim.x) {
    float s = p[a].y;
    if (score_bin(s) >= t) {
      int pos = atomicAdd(&lcnt, 1);
      unsigned int ib = ~__float_as_uint(s); // score>=0: ~bits ascending == score descending
      lbuf[pos] = ((ull)ib << 32) | (unsigned int)a;
    }
  }
  __syncthreads();
  if (threadIdx.x == 0) lbase = atomicAdd(&cnt[b * 16], lcnt);
  __syncthreads();
  int n = lcnt, base = lbase;
  ull* kb = keys + (size_t)b * CAP;
  for (int i = threadIdx.x; i < n; i += 256) {
    int pos = base + i;
    if (pos < CAP) kb[pos] = lbuf[i];
  }
}

// ---------------- 4a. rank by counting ----------------
__global__ __launch_bounds__(256) void rank_kernel(const int* __restrict__ cnt,
                                                   const ull* __restrict__ keys,
                                                   unsigned int* __restrict__ rank) {
  int b = blockIdx.z;
  int n = cnt[b * 16];
  if (n > CAP) n = CAP;
  int i = blockIdx.x * 256 + threadIdx.x;
  if (i >= n) return;
  const ull* kb = keys + (size_t)b * CAP;
  ull my = kb[i];
  int n16 = (n + 15) & ~15;
  int nchunks = n16 >> 4;
  int hc = nchunks >> 1;
  int jlo = (blockIdx.y == 0) ? 0 : hc * 16;
  int jhi = (blockIdx.y == 0) ? hc * 16 : n16;
  unsigned int r = 0;
  for (int j = jlo; j < jhi; j += 16) {
#pragma unroll
    for (int t = 0; t < 16; ++t) {
      r += (kb[j + t] < my) ? 1u : 0u;
    }
  }
  if (r) atomicAdd(&rank[(size_t)b * CAP + i], r);
}

// ---------------- 4b. scatter + box decode ----------------
__global__ __launch_bounds__(256) void scatter_kernel(const float4* __restrict__ anchors4,
                                                      const float4* __restrict__ bbox4,
                                                      const int* __restrict__ cnt,
                                                      const ull* __restrict__ keys,
                                                      const unsigned int* __restrict__ rank,
                                                      float4* __restrict__ boxes4) {
#pragma clang fp contract(off)
  int b = blockIdx.y;
  int n = cnt[b * 16];
  if (n > CAP) n = CAP;
  int i = blockIdx.x * 256 + threadIdx.x;
  if (i >= n) return;
  unsigned int r = rank[(size_t)b * CAP + i];
  if (r >= (unsigned)KSEL) return;
  int a = (int)(unsigned int)(keys[(size_t)b * CAP + i] & 0xffffffffull);
  float4 anc = anchors4[(size_t)b * NA + a];
  float4 d   = bbox4[(size_t)b * NA + a];
  float h = anc.z - anc.x;
  float w = anc.w - anc.y;
  float dy = d.x * 0.1f, dx = d.y * 0.1f, dh = d.z * 0.2f, dw = d.w * 0.2f;
  float cy = (anc.x + (0.5f * h)) + (dy * h);
  float cx = (anc.y + (0.5f * w)) + (dx * w);
  float h2 = h * expf(dh);
  float w2 = w * expf(dw);
  float y1 = cy - 0.5f * h2;
  float x1 = cx - 0.5f * w2;
  float y2 = y1 + h2;
  float x2 = x1 + w2;
  y1 = fminf(fmaxf(y1, 0.f), 1.f);
  x1 = fminf(fmaxf(x1, 0.f), 1.f);
  y2 = fminf(fmaxf(y2, 0.f), 1.f);
  x2 = fminf(fmaxf(x2, 0.f), 1.f);
  boxes4[(size_t)b * KSEL + r] = make_float4(y1, x1, y2, x2);
}

// ---------------- 5. suppression mask, ROW-major [b][row][96] words ----------------
// 16 VALU/pair: ca hoisted to LDS; d = fmaf(-0.7, uni, inter) single-rounding;
// guard band 6e-7*uni (error bound ~1.7e-7*uni) -> exact IEEE division only on ties.
__global__ __launch_bounds__(256) void mask_kernel(const float4* __restrict__ boxes4,
                                                   ull* __restrict__ mask) {
  int cx = blockIdx.x, rb = blockIdx.y, b = blockIdx.z;
  int cb0 = rb + 4 * cx;
  if (cb0 >= NWP) return;
  __shared__ float4 colbox[4][64];
  __shared__ float colca[4][64];
  __shared__ ull wtile[64][5];
  int tid = threadIdx.x, wv = tid >> 6, l = tid & 63;
  int cb = cb0 + wv;
  int row = rb * 64 + l;
  float4 r = (row < KSEL) ? boxes4[(size_t)b * KSEL + row] : make_float4(0.f, 0.f, 0.f, 0.f);
  float ra = (r.z - r.x) * (r.w - r.y);
  int c = cb * 64 + l;
  float4 cload = (cb < NB && c < KSEL) ? boxes4[(size_t)b * KSEL + c]
                                       : make_float4(0.f, 0.f, 0.f, 0.f);
  colbox[wv][l] = cload;
  colca[wv][l] = (cload.z - cload.x) * (cload.w - cload.y);
  __syncthreads();
  ull bits = 0ull;
  if (cb < NB) {
#pragma unroll
    for (int u = 0; u < 64; ++u) {
      float4 cbx = colbox[wv][u];
      float ca = colca[wv][u];
      float ih = fmaxf(fminf(r.z, cbx.z) - fmaxf(r.x, cbx.x), 0.f);
      float iw = fmaxf(fminf(r.w, cbx.w) - fmaxf(r.y, cbx.y), 0.f);
      float inter = ih * iw;
      float s = ra + ca;
      float uni = s - inter;
      float d = fmaf(-0.7f, uni, inter);
      float tt = 6e-7f * uni;
      bool keep;
      if (__builtin_fabsf(d) <= tt) {
        keep = (inter / uni) > 0.7f;   // exact tie-region path (rare; 0/0->NaN->false)
      } else {
        keep = d > 0.f;
      }
      if (keep) bits |= (1ull << u);
    }
    if (cb == rb) {
      bits &= (l == 63) ? 0ull : (~0ull << (l + 1)); // only cc > row suppress
    }
  }
  wtile[l][wv] = bits;
  __syncthreads();
  int nrows = min(64, KSEL - rb * 64);
  int rr = tid >> 2, w = tid & 3;
  if (rr < nrows && cb0 + w < NWP)
    mask[((size_t)b * KSEL + (size_t)(rb * 64 + rr)) * NWP + cb0 + w] = wtile[rr][w];
}

// ---------------- 6. single-wave scan, kept-rows-only lag-1 OR ----------------
// Per block n: [1] OR the 16 loop-carried slots holding kept(n-1) rows' lane-words
// (loop-carried PHIs -> compiler must keep them resident; latency hidden by a full
// block), [2] SALU ctz/readlane decision, [3] prefetch next diag column, [4] issue
// slot loads for rows just kept (~11 avg). S-word n+1 is complete at decision(n+1)
// because kept(n) is ORed at [1] of n+1; words >= n+2 have >=1 block of slack.
__global__ __launch_bounds__(64, 1) void scan_kernel(const float4* __restrict__ boxes4,
                                                     const ull* __restrict__ mask,
                                                     float4* __restrict__ out4) {
  __shared__ int skeep[PROP];
  int b = blockIdx.x;
  int lane = threadIdx.x;
  const ull* mb = mask + (size_t)b * KSEL * NWP;
  int col = (2 * lane < NB) ? 2 * lane : NB;   // lanes >=47 -> pad words 94,95 (zeros)

  ull Sx = 0ull, Sy = 0ull;                    // suppressed words 2*lane, 2*lane+1
  int kept = 0;
  bool done = false;

  ulonglong2 zz; zz.x = 0ull; zz.y = 0ull;
  ulonglong2 s0=zz,s1=zz,s2=zz,s3=zz,s4=zz,s5=zz,s6=zz,s7=zz,
             s8=zz,s9=zz,s10=zz,s11=zz,s12=zz,s13=zz,s14=zz,s15=zz;
  unsigned smv = 0;                            // slot-valid bits (prev block's kept)

  ull dg = mb[(size_t)lane * NWP + 0];         // block 0 diagonal word (row=lane)

  for (int n = 0; n < NBLK && !done; ++n) {
    int i0 = n * 64;

    // [1] OR previous block's kept slots into distributed S
    {
      ull m;
      m = 0ull - (ull)((smv >> 0) & 1u);  Sx |= s0.x & m;  Sy |= s0.y & m;
      m = 0ull - (ull)((smv >> 1) & 1u);  Sx |= s1.x & m;  Sy |= s1.y & m;
      m = 0ull - (ull)((smv >> 2) & 1u);  Sx |= s2.x & m;  Sy |= s2.y & m;
      m = 0ull - (ull)((smv >> 3) & 1u);  Sx |= s3.x & m;  Sy |= s3.y & m;
      m = 0ull - (ull)((smv >> 4) & 1u);  Sx |= s4.x & m;  Sy |= s4.y & m;
      m = 0ull - (ull)((smv >> 5) & 1u);  Sx |= s5.x & m;  Sy |= s5.y & m;
      m = 0ull - (ull)((smv >> 6) & 1u);  Sx |= s6.x & m;  Sy |= s6.y & m;
      m = 0ull - (ull)((smv >> 7) & 1u);  Sx |= s7.x & m;  Sy |= s7.y & m;
      m = 0ull - (ull)((smv >> 8) & 1u);  Sx |= s8.x & m;  Sy |= s8.y & m;
      m = 0ull - (ull)((smv >> 9) & 1u);  Sx |= s9.x & m;  Sy |= s9.y & m;
      m = 0ull - (ull)((smv >> 10) & 1u); Sx |= s10.x & m; Sy |= s10.y & m;
      m = 0ull - (ull)((smv >> 11) & 1u); Sx |= s11.x & m; Sy |= s11.y & m;
      m = 0ull - (ull)((smv >> 12) & 1u); Sx |= s12.x & m; Sy |= s12.y & m;
      m = 0ull - (ull)((smv >> 13) & 1u); Sx |= s13.x & m; Sy |= s13.y & m;
      m = 0ull - (ull)((smv >> 14) & 1u); Sx |= s14.x & m; Sy |= s14.y & m;
      m = 0ull - (ull)((smv >> 15) & 1u); Sx |= s15.x & m; Sy |= s15.y & m;
    }
    asm volatile("" : : "v"(dg));

    // [2] scalar greedy decision for this block
    int ol = n >> 1;
    ull Ssel = (n & 1) ? Sy : Sx;
    unsigned slo = (unsigned)__builtin_amdgcn_readlane((int)(unsigned)Ssel, ol);
    unsigned shi = (unsigned)__builtin_amdgcn_readlane((int)(unsigned)(Ssel >> 32), ol);
    ull Sw = (ull)slo | ((ull)shi << 32);
    int nval = KSEL - i0;
    ull valid = (nval >= 64) ? ~0ull : ((1ull << nval) - 1ull);
    ull A = ~Sw & valid;
    ull K = 0ull;
    unsigned vlo = (unsigned)dg, vhi = (unsigned)(dg >> 32);

    while (A) {
      int u = __builtin_ctzll(A);
      if (lane == 0) skeep[kept] = i0 + u;
      ++kept;
      K |= (1ull << u);
      if (kept >= PROP) { done = true; break; }
      ull Mu = (ull)(unsigned)__builtin_amdgcn_readlane((int)vlo, u)
             | ((ull)(unsigned)__builtin_amdgcn_readlane((int)vhi, u) << 32);
      A &= ~(Mu | (1ull << u));
    }

    // [3] next block's diagonal prefetch
    ull dgN = 0ull;
    if (n + 1 < NBLK) {
      int rn = (n + 1) * 64 + lane;
      if (rn >= KSEL) rn = KSEL - 1;
      dgN = mb[(size_t)rn * NWP + (n + 1)];
    }

    // [4] issue slot loads for this block's kept rows (consumed at [1] next iter)
    smv = 0;
    if (!done) {
      ull kk = K;
      int cntK = __builtin_popcountll(K);
#define SLOT_LOAD(SV) { int u_ = kk ? __builtin_ctzll(kk) : 0; kk &= (kk - 1ull); \
                        SV = *(const ulonglong2*)(mb + (size_t)(i0 + u_) * NWP + col); }
      SLOT_LOAD(s0)  SLOT_LOAD(s1)  SLOT_LOAD(s2)  SLOT_LOAD(s3)
      SLOT_LOAD(s4)  SLOT_LOAD(s5)  SLOT_LOAD(s6)  SLOT_LOAD(s7)
      SLOT_LOAD(s8)  SLOT_LOAD(s9)  SLOT_LOAD(s10) SLOT_LOAD(s11)
      SLOT_LOAD(s12) SLOT_LOAD(s13) SLOT_LOAD(s14) SLOT_LOAD(s15)
#undef SLOT_LOAD
      smv = (cntK >= 16) ? 0xFFFFu : ((1u << cntK) - 1u);
      // rare overflow (>16 kept in one block): OR immediately
      while (kk) {
        int u_ = __builtin_ctzll(kk);
        kk &= (kk - 1ull);
        ulonglong2 v = *(const ulonglong2*)(mb + (size_t)(i0 + u_) * NWP + col);
        Sx |= v.x; Sy |= v.y;
      }
    }
    dg = dgN;
  }

  __syncthreads();
  int fin = kept;
  for (int rr2 = lane; rr2 < PROP; rr2 += 64) {
    float4 v = make_float4(0.f, 0.f, 0.f, 0.f);
    if (rr2 < fin) v = boxes4[(size_t)b * KSEL + skeep[rr2]];
    out4[(size_t)b * PROP + rr2] = v;
  }
}

// ---------------- launch ----------------
extern "C" void kernel_launch(void* const* d_in, const int* in_sizes, int n_in,
                              void* d_out, int out_size, void* d_ws, size_t ws_size,
                              hipStream_t stream) {
  const float2* probs   = (const float2*)d_in[0];
  const float4* bbox4   = (const float4*)d_in[1];
  const float4* anchors4= (const float4*)d_in[2];
  float4* out4 = (float4*)d_out;
  char* ws = (char*)d_ws;

  int* cnt           = (int*)(ws + OFF_CNT);
  int* tsel          = (int*)(ws + OFF_TSEL);
  float4* boxes4     = (float4*)(ws + OFF_BOXES);
  ull* maskw         = (ull*)(ws + OFF_MASK);
  ull* keys          = (ull*)(ws + OFF_KEYS);
  unsigned int* rank = (unsigned int*)(ws + OFF_RANK);
  unsigned int* hist = (unsigned int*)(ws + OFF_HIST);

  hipMemsetAsync(ws + OFF_CNT, 0, 544, stream);
  hipMemsetAsync(ws + OFF_KEYS, 0xFF, 524288, stream);  // pad keys = +inf
  hipMemsetAsync(ws + OFF_RANK, 0, 262144, stream);

  hipLaunchKernelGGL(hist_kernel,    dim3(HB, BATCH),     dim3(256), 0, stream, probs, hist);
  hipLaunchKernelGGL(thresh_kernel,  dim3(BATCH),         dim3(256), 0, stream, hist, tsel);
  hipLaunchKernelGGL(compact_kernel, dim3(128, BATCH),    dim3(256), 0, stream, probs, tsel, cnt, keys);
  hipLaunchKernelGGL(rank_kernel,    dim3(32, 2, BATCH),  dim3(256), 0, stream, cnt, keys, rank);
  hipLaunchKernelGGL(scatter_kernel, dim3(32, BATCH),     dim3(256), 0, stream, anchors4, bbox4, cnt, keys, rank, boxes4);
  hipLaunchKernelGGL(mask_kernel,    dim3(24, NB, BATCH), dim3(256), 0, stream, boxes4, maskw);
  hipLaunchKernelGGL(scan_kernel,    dim3(BATCH),         dim3(64),  0, stream, boxes4, maskw, out4);
}

// Round 11
// 540.195 us; speedup vs baseline: 1.0092x; 1.0092x over previous
//
#include <hip/hip_runtime.h>
#include <hip/hip_bf16.h>

typedef unsigned long long ull;
typedef __attribute__((ext_vector_type(4))) unsigned int u32x4;

// ---------------- problem constants ----------------
constexpr int BATCH = 8;
constexpr int NA    = 261888;
constexpr int KSEL  = 6000;          // PRE_NMS_LIMIT
constexpr int PROP  = 1000;          // PROPOSAL_COUNT
constexpr int CAP   = 8192;          // candidate capacity
constexpr int NBINS = 8192;          // histogram bins
constexpr int HB    = 16;            // private histogram blocks per batch
constexpr int NB    = (KSEL + 63) / 64;   // 94 mask words per row
constexpr int NWP   = 96;            // padded words per row (96*8 = 768B rows)
constexpr int NBLK  = (KSEL + 63) / 64;   // 94 row-blocks

// workspace layout (bytes). keys/rank/hist all live in the (later) mask region,
// at non-overlapping offsets; all die before mask_kernel writes.
constexpr size_t OFF_CNT   = 0;                       // 8*16*4 = 512
constexpr size_t OFF_TSEL  = 512;                     // 32
constexpr size_t OFF_BOXES = 544;                     // 8*6000*16 = 768000
constexpr size_t OFF_MASK  = 769024;                  // 8*6000*96*8 = 36864000
constexpr size_t OFF_KEYS  = OFF_MASK;                // 8*8192*8 = 524288
constexpr size_t OFF_RANK  = OFF_MASK + 524288;       // 8*8192*4 = 262144
constexpr size_t OFF_HIST  = OFF_MASK + 2097152;      // 4MB
// total = 37,633,024 B

__device__ __forceinline__ int score_bin(float s) {
  int b = (int)(s * (float)NBINS);
  if (b < 0) b = 0;
  if (b > NBINS - 1) b = NBINS - 1;
  return b;
}

// ---------------- 1. histogram (private per-block copies, no global atomics) ----------------
__global__ __launch_bounds__(256) void hist_kernel(const float2* __restrict__ probs,
                                                   unsigned int* __restrict__ hist) {
  __shared__ unsigned int lh[NBINS];
  for (int i = threadIdx.x; i < NBINS; i += 256) lh[i] = 0u;
  __syncthreads();
  int b = blockIdx.y;
  const float2* p = probs + (size_t)b * NA;
  for (int a = blockIdx.x * 256 + threadIdx.x; a < NA; a += HB * 256) {
    atomicAdd(&lh[score_bin(p[a].y)], 1u);
  }
  __syncthreads();
  unsigned int* gh = hist + ((size_t)b * HB + blockIdx.x) * NBINS;
  for (int i = threadIdx.x; i < NBINS; i += 256) gh[i] = lh[i];
}

// ---------------- 2. threshold bin select ----------------
__global__ __launch_bounds__(256) void thresh_kernel(const unsigned int* __restrict__ hist,
                                                     int* __restrict__ tsel) {
  constexpr int GR = NBINS / 256; // 32 bins per thread
  __shared__ unsigned int ch[NBINS];
  __shared__ unsigned int gsum[256];
  int b = blockIdx.x;
  const unsigned int* h = hist + (size_t)b * HB * NBINS;
  for (int bin = threadIdx.x; bin < NBINS; bin += 256) {
    unsigned int s = 0;
    for (int k = 0; k < HB; ++k) s += h[(size_t)k * NBINS + bin];
    ch[bin] = s;
  }
  __syncthreads();
  unsigned int s = 0;
  int g0 = threadIdx.x * GR;
  for (int i = 0; i < GR; ++i) s += ch[g0 + i];
  gsum[threadIdx.x] = s;
  __syncthreads();
  if (threadIdx.x == 0) {
    unsigned int acc = 0;
    int g = 255;
    for (; g > 0; --g) {
      if (acc + gsum[g] >= (unsigned)KSEL) break;
      acc += gsum[g];
    }
    int t = g * GR;
    for (int bin = g * GR + GR - 1; bin >= g * GR; --bin) {
      acc += ch[bin];
      if (acc >= (unsigned)KSEL) { t = bin; break; }
    }
    tsel[b] = t;
  }
}

// ---------------- 3. compact candidates (block-aggregated, 1 global atomic/block) ----------------
__global__ __launch_bounds__(256) void compact_kernel(const float2* __restrict__ probs,
                                                      const int* __restrict__ tsel,
                                                      int* __restrict__ cnt,
                                                      ull* __restrict__ keys) {
  __shared__ int lcnt, lbase;
  __shared__ ull lbuf[2048]; // block covers <=2048 anchors
  int b = blockIdx.y;
  int t = tsel[b];
  if (threadIdx.x == 0) lcnt = 0;
  __syncthreads();
  const float2* p = probs + (size_t)b * NA;
  for (int a = blockIdx.x * blockDim.x + threadIdx.x; a < NA; a += gridDim.x * blockDim.x) {
    float s = p[a].y;
    if (score_bin(s) >= t) {
      int pos = atomicAdd(&lcnt, 1);
      unsigned int ib = ~__float_as_uint(s); // score>=0: ~bits ascending == score descending
      lbuf[pos] = ((ull)ib << 32) | (unsigned int)a;
    }
  }
  __syncthreads();
  if (threadIdx.x == 0) lbase = atomicAdd(&cnt[b * 16], lcnt);
  __syncthreads();
  int n = lcnt, base = lbase;
  ull* kb = keys + (size_t)b * CAP;
  for (int i = threadIdx.x; i < n; i += 256) {
    int pos = base + i;
    if (pos < CAP) kb[pos] = lbuf[i];
  }
}

// ---------------- 4a. rank by counting ----------------
__global__ __launch_bounds__(256) void rank_kernel(const int* __restrict__ cnt,
                                                   const ull* __restrict__ keys,
                                                   unsigned int* __restrict__ rank) {
  int b = blockIdx.z;
  int n = cnt[b * 16];
  if (n > CAP) n = CAP;
  int i = blockIdx.x * 256 + threadIdx.x;
  if (i >= n) return;
  const ull* kb = keys + (size_t)b * CAP;
  ull my = kb[i];
  int n16 = (n + 15) & ~15;
  int nchunks = n16 >> 4;
  int hc = nchunks >> 1;
  int jlo = (blockIdx.y == 0) ? 0 : hc * 16;
  int jhi = (blockIdx.y == 0) ? hc * 16 : n16;
  unsigned int r = 0;
  for (int j = jlo; j < jhi; j += 16) {
#pragma unroll
    for (int t = 0; t < 16; ++t) {
      r += (kb[j + t] < my) ? 1u : 0u;
    }
  }
  if (r) atomicAdd(&rank[(size_t)b * CAP + i], r);
}

// ---------------- 4b. scatter + box decode ----------------
__global__ __launch_bounds__(256) void scatter_kernel(const float4* __restrict__ anchors4,
                                                      const float4* __restrict__ bbox4,
                                                      const int* __restrict__ cnt,
                                                      const ull* __restrict__ keys,
                                                      const unsigned int* __restrict__ rank,
                                                      float4* __restrict__ boxes4) {
#pragma clang fp contract(off)
  int b = blockIdx.y;
  int n = cnt[b * 16];
  if (n > CAP) n = CAP;
  int i = blockIdx.x * 256 + threadIdx.x;
  if (i >= n) return;
  unsigned int r = rank[(size_t)b * CAP + i];
  if (r >= (unsigned)KSEL) return;
  int a = (int)(unsigned int)(keys[(size_t)b * CAP + i] & 0xffffffffull);
  float4 anc = anchors4[(size_t)b * NA + a];
  float4 d   = bbox4[(size_t)b * NA + a];
  float h = anc.z - anc.x;
  float w = anc.w - anc.y;
  float dy = d.x * 0.1f, dx = d.y * 0.1f, dh = d.z * 0.2f, dw = d.w * 0.2f;
  float cy = (anc.x + (0.5f * h)) + (dy * h);
  float cx = (anc.y + (0.5f * w)) + (dx * w);
  float h2 = h * expf(dh);
  float w2 = w * expf(dw);
  float y1 = cy - 0.5f * h2;
  float x1 = cx - 0.5f * w2;
  float y2 = y1 + h2;
  float x2 = x1 + w2;
  y1 = fminf(fmaxf(y1, 0.f), 1.f);
  x1 = fminf(fmaxf(x1, 0.f), 1.f);
  y2 = fminf(fmaxf(y2, 0.f), 1.f);
  x2 = fminf(fmaxf(x2, 0.f), 1.f);
  boxes4[(size_t)b * KSEL + r] = make_float4(y1, x1, y2, x2);
}

// ---------------- 5. suppression mask, ROW-major [b][row][96] words ----------------
// 16 VALU/pair: ca hoisted to LDS; d = fmaf(-0.7, uni, inter) single-rounding;
// guard band 6e-7*uni (error bound ~1.7e-7*uni) -> exact IEEE division only on ties.
__global__ __launch_bounds__(256) void mask_kernel(const float4* __restrict__ boxes4,
                                                   ull* __restrict__ mask) {
  int cx = blockIdx.x, rb = blockIdx.y, b = blockIdx.z;
  int cb0 = rb + 4 * cx;
  if (cb0 >= NWP) return;
  __shared__ float4 colbox[4][64];
  __shared__ float colca[4][64];
  __shared__ ull wtile[64][5];
  int tid = threadIdx.x, wv = tid >> 6, l = tid & 63;
  int cb = cb0 + wv;
  int row = rb * 64 + l;
  float4 r = (row < KSEL) ? boxes4[(size_t)b * KSEL + row] : make_float4(0.f, 0.f, 0.f, 0.f);
  float ra = (r.z - r.x) * (r.w - r.y);
  int c = cb * 64 + l;
  float4 cload = (cb < NB && c < KSEL) ? boxes4[(size_t)b * KSEL + c]
                                       : make_float4(0.f, 0.f, 0.f, 0.f);
  colbox[wv][l] = cload;
  colca[wv][l] = (cload.z - cload.x) * (cload.w - cload.y);
  __syncthreads();
  ull bits = 0ull;
  if (cb < NB) {
#pragma unroll
    for (int u = 0; u < 64; ++u) {
      float4 cbx = colbox[wv][u];
      float ca = colca[wv][u];
      float ih = fmaxf(fminf(r.z, cbx.z) - fmaxf(r.x, cbx.x), 0.f);
      float iw = fmaxf(fminf(r.w, cbx.w) - fmaxf(r.y, cbx.y), 0.f);
      float inter = ih * iw;
      float s = ra + ca;
      float uni = s - inter;
      float d = fmaf(-0.7f, uni, inter);
      float tt = 6e-7f * uni;
      bool keep;
      if (__builtin_fabsf(d) <= tt) {
        keep = (inter / uni) > 0.7f;   // exact tie-region path (rare; 0/0->NaN->false)
      } else {
        keep = d > 0.f;
      }
      if (keep) bits |= (1ull << u);
    }
    if (cb == rb) {
      bits &= (l == 63) ? 0ull : (~0ull << (l + 1)); // only cc > row suppress
    }
  }
  wtile[l][wv] = bits;
  __syncthreads();
  int nrows = min(64, KSEL - rb * 64);
  int rr = tid >> 2, w = tid & 3;
  if (rr < nrows && cb0 + w < NWP)
    mask[((size_t)b * KSEL + (size_t)(rb * 64 + rr)) * NWP + cb0 + w] = wtile[rr][w];
}

// ---------------- 6. single-wave scan, lag-1 kept-rows OR, ASM-PINNED slot loads ----------------
// The slot loads are inline `asm volatile global_load_dwordx4` -> the compiler cannot
// sink/rematerialize them (rounds 6/8/10 all lost to load sinking). Data quads stay
// live across the iteration boundary; consumed after s_waitcnt vmcnt(0) +
// sched_barrier(0) (rule: reg-only consumers can be hoisted past an asm waitcnt).
__global__ __launch_bounds__(64, 1) void scan_kernel(const float4* __restrict__ boxes4,
                                                     const ull* __restrict__ mask,
                                                     float4* __restrict__ out4) {
  __shared__ int skeep[PROP];
  int b = blockIdx.x;
  int lane = threadIdx.x;
  const ull* mb = mask + (size_t)b * KSEL * NWP;
  int col = (2 * lane < NB) ? 2 * lane : NB;   // lanes >=47 -> pad words 94,95 (zeros)

  ull Sx = 0ull, Sy = 0ull;                    // suppressed words 2*lane, 2*lane+1
  int kept = 0;
  bool done = false;

  u32x4 s0{0,0,0,0}, s1{0,0,0,0}, s2{0,0,0,0}, s3{0,0,0,0},
        s4{0,0,0,0}, s5{0,0,0,0}, s6{0,0,0,0}, s7{0,0,0,0},
        s8{0,0,0,0}, s9{0,0,0,0}, s10{0,0,0,0}, s11{0,0,0,0},
        s12{0,0,0,0}, s13{0,0,0,0}, s14{0,0,0,0}, s15{0,0,0,0};
  unsigned smv = 0;                            // slot-valid bits (prev block's kept)

  ull dg = mb[(size_t)lane * NWP + 0];         // block 0 diagonal word (row=lane)

  for (int n = 0; n < NBLK && !done; ++n) {
    int i0 = n * 64;

    // [1] drain slot loads issued at [4] of the previous iteration, then OR them in.
    asm volatile("s_waitcnt vmcnt(0)" ::: "memory");
    __builtin_amdgcn_sched_barrier(0);
    {
      ull m;
#define SLOT_OR(SV, BIT) \
      m = 0ull - (ull)((smv >> BIT) & 1u); \
      Sx |= (((ull)SV.y << 32) | (ull)SV.x) & m; \
      Sy |= (((ull)SV.w << 32) | (ull)SV.z) & m;
      SLOT_OR(s0, 0)  SLOT_OR(s1, 1)  SLOT_OR(s2, 2)  SLOT_OR(s3, 3)
      SLOT_OR(s4, 4)  SLOT_OR(s5, 5)  SLOT_OR(s6, 6)  SLOT_OR(s7, 7)
      SLOT_OR(s8, 8)  SLOT_OR(s9, 9)  SLOT_OR(s10,10) SLOT_OR(s11,11)
      SLOT_OR(s12,12) SLOT_OR(s13,13) SLOT_OR(s14,14) SLOT_OR(s15,15)
#undef SLOT_OR
    }

    // [2] scalar greedy decision for this block
    int ol = n >> 1;
    ull Ssel = (n & 1) ? Sy : Sx;
    unsigned slo = (unsigned)__builtin_amdgcn_readlane((int)(unsigned)Ssel, ol);
    unsigned shi = (unsigned)__builtin_amdgcn_readlane((int)(unsigned)(Ssel >> 32), ol);
    ull Sw = (ull)slo | ((ull)shi << 32);
    int nval = KSEL - i0;
    ull valid = (nval >= 64) ? ~0ull : ((1ull << nval) - 1ull);
    ull A = ~Sw & valid;
    ull K = 0ull;
    unsigned vlo = (unsigned)dg, vhi = (unsigned)(dg >> 32);

    while (A) {
      int u = __builtin_ctzll(A);
      if (lane == 0) skeep[kept] = i0 + u;
      ++kept;
      K |= (1ull << u);
      if (kept >= PROP) { done = true; break; }
      ull Mu = (ull)(unsigned)__builtin_amdgcn_readlane((int)vlo, u)
             | ((ull)(unsigned)__builtin_amdgcn_readlane((int)vhi, u) << 32);
      A &= ~(Mu | (1ull << u));
    }

    // [3] next block's diagonal prefetch (normal load; compiler-managed wait at [2])
    ull dgN = 0ull;
    if (n + 1 < NBLK) {
      int rn = (n + 1) * 64 + lane;
      if (rn >= KSEL) rn = KSEL - 1;
      dgN = mb[(size_t)rn * NWP + (n + 1)];
    }

    // [4] issue ASM-pinned slot loads for this block's kept rows (consumed at [1] next iter)
    smv = 0;
    if (!done) {
      ull kk = K;
      int cntK = __builtin_popcountll(K);
#define SLOT_LOAD(SV) { int u_ = kk ? __builtin_ctzll(kk) : 0; kk &= (kk - 1ull); \
                        const void* p_ = (const void*)(mb + (size_t)(i0 + u_) * NWP + col); \
                        asm volatile("global_load_dwordx4 %0, %1, off" \
                                     : "=&v"(SV) : "v"(p_) : "memory"); }
      SLOT_LOAD(s0)  SLOT_LOAD(s1)  SLOT_LOAD(s2)  SLOT_LOAD(s3)
      SLOT_LOAD(s4)  SLOT_LOAD(s5)  SLOT_LOAD(s6)  SLOT_LOAD(s7)
      SLOT_LOAD(s8)  SLOT_LOAD(s9)  SLOT_LOAD(s10) SLOT_LOAD(s11)
      SLOT_LOAD(s12) SLOT_LOAD(s13) SLOT_LOAD(s14) SLOT_LOAD(s15)
#undef SLOT_LOAD
      smv = (cntK >= 16) ? 0xFFFFu : ((1u << cntK) - 1u);
      // rare overflow (>16 kept in one block): OR immediately via normal loads
      while (kk) {
        int u_ = __builtin_ctzll(kk);
        kk &= (kk - 1ull);
        ulonglong2 v = *(const ulonglong2*)(mb + (size_t)(i0 + u_) * NWP + col);
        Sx |= v.x; Sy |= v.y;
      }
    }
    dg = dgN;
  }

  __syncthreads();
  int fin = kept;
  for (int rr2 = lane; rr2 < PROP; rr2 += 64) {
    float4 v = make_float4(0.f, 0.f, 0.f, 0.f);
    if (rr2 < fin) v = boxes4[(size_t)b * KSEL + skeep[rr2]];
    out4[(size_t)b * PROP + rr2] = v;
  }
}

// ---------------- launch ----------------
extern "C" void kernel_launch(void* const* d_in, const int* in_sizes, int n_in,
                              void* d_out, int out_size, void* d_ws, size_t ws_size,
                              hipStream_t stream) {
  const float2* probs   = (const float2*)d_in[0];
  const float4* bbox4   = (const float4*)d_in[1];
  const float4* anchors4= (const float4*)d_in[2];
  float4* out4 = (float4*)d_out;
  char* ws = (char*)d_ws;

  int* cnt           = (int*)(ws + OFF_CNT);
  int* tsel          = (int*)(ws + OFF_TSEL);
  float4* boxes4     = (float4*)(ws + OFF_BOXES);
  ull* maskw         = (ull*)(ws + OFF_MASK);
  ull* keys          = (ull*)(ws + OFF_KEYS);
  unsigned int* rank = (unsigned int*)(ws + OFF_RANK);
  unsigned int* hist = (unsigned int*)(ws + OFF_HIST);

  hipMemsetAsync(ws + OFF_CNT, 0, 544, stream);
  hipMemsetAsync(ws + OFF_KEYS, 0xFF, 524288, stream);  // pad keys = +inf
  hipMemsetAsync(ws + OFF_RANK, 0, 262144, stream);

  hipLaunchKernelGGL(hist_kernel,    dim3(HB, BATCH),     dim3(256), 0, stream, probs, hist);
  hipLaunchKernelGGL(thresh_kernel,  dim3(BATCH),         dim3(256), 0, stream, hist, tsel);
  hipLaunchKernelGGL(compact_kernel, dim3(128, BATCH),    dim3(256), 0, stream, probs, tsel, cnt, keys);
  hipLaunchKernelGGL(rank_kernel,    dim3(32, 2, BATCH),  dim3(256), 0, stream, cnt, keys, rank);
  hipLaunchKernelGGL(scatter_kernel, dim3(32, BATCH),     dim3(256), 0, stream, anchors4, bbox4, cnt, keys, rank, boxes4);
  hipLaunchKernelGGL(mask_kernel,    dim3(24, NB, BATCH), dim3(256), 0, stream, boxes4, maskw);
  hipLaunchKernelGGL(scan_kernel,    dim3(BATCH),         dim3(64),  0, stream, boxes4, maskw, out4);
}

// Round 13
// 506.176 us; speedup vs baseline: 1.0770x; 1.0672x over previous
//
#include <hip/hip_runtime.h>
#include <hip/hip_bf16.h>

typedef unsigned long long ull;
typedef __attribute__((ext_vector_type(4))) unsigned int u32x4;
typedef __attribute__((ext_vector_type(2))) unsigned int u32x2;

// ---------------- problem constants ----------------
constexpr int BATCH = 8;
constexpr int NA    = 261888;
constexpr int KSEL  = 6000;          // PRE_NMS_LIMIT
constexpr int PROP  = 1000;          // PROPOSAL_COUNT
constexpr int CAP   = 8192;          // candidate capacity
constexpr int NBINS = 8192;          // histogram bins
constexpr int HB    = 16;            // private histogram blocks per batch
constexpr int NB    = (KSEL + 63) / 64;   // 94 mask words per row
constexpr int NWP   = 96;            // padded words per row (96*8 = 768B rows)
constexpr int NBLK  = (KSEL + 63) / 64;   // 94 row-blocks (even)

// workspace layout (bytes). keys/rank/hist all alias the (later) mask region.
constexpr size_t OFF_CNT   = 0;                       // 8*16*4 = 512
constexpr size_t OFF_TSEL  = 512;                     // 32
constexpr size_t OFF_BOXES = 544;                     // 8*6000*16 = 768000
constexpr size_t OFF_MASK  = 769024;                  // 8*6000*96*8 = 36864000
constexpr size_t OFF_KEYS  = OFF_MASK;                // 8*8192*8 = 524288
constexpr size_t OFF_RANK  = OFF_MASK + 524288;       // 8*8192*4 = 262144
constexpr size_t OFF_HIST  = OFF_MASK + 2097152;      // 4MB
// total = 37,633,024 B

__device__ __forceinline__ int score_bin(float s) {
  int b = (int)(s * (float)NBINS);
  if (b < 0) b = 0;
  if (b > NBINS - 1) b = NBINS - 1;
  return b;
}

// ---------------- 1. histogram ----------------
__global__ __launch_bounds__(256) void hist_kernel(const float2* __restrict__ probs,
                                                   unsigned int* __restrict__ hist) {
  __shared__ unsigned int lh[NBINS];
  for (int i = threadIdx.x; i < NBINS; i += 256) lh[i] = 0u;
  __syncthreads();
  int b = blockIdx.y;
  const float2* p = probs + (size_t)b * NA;
  for (int a = blockIdx.x * 256 + threadIdx.x; a < NA; a += HB * 256) {
    atomicAdd(&lh[score_bin(p[a].y)], 1u);
  }
  __syncthreads();
  unsigned int* gh = hist + ((size_t)b * HB + blockIdx.x) * NBINS;
  for (int i = threadIdx.x; i < NBINS; i += 256) gh[i] = lh[i];
}

// ---------------- 2. threshold bin select ----------------
__global__ __launch_bounds__(256) void thresh_kernel(const unsigned int* __restrict__ hist,
                                                     int* __restrict__ tsel) {
  constexpr int GR = NBINS / 256;
  __shared__ unsigned int ch[NBINS];
  __shared__ unsigned int gsum[256];
  int b = blockIdx.x;
  const unsigned int* h = hist + (size_t)b * HB * NBINS;
  for (int bin = threadIdx.x; bin < NBINS; bin += 256) {
    unsigned int s = 0;
    for (int k = 0; k < HB; ++k) s += h[(size_t)k * NBINS + bin];
    ch[bin] = s;
  }
  __syncthreads();
  unsigned int s = 0;
  int g0 = threadIdx.x * GR;
  for (int i = 0; i < GR; ++i) s += ch[g0 + i];
  gsum[threadIdx.x] = s;
  __syncthreads();
  if (threadIdx.x == 0) {
    unsigned int acc = 0;
    int g = 255;
    for (; g > 0; --g) {
      if (acc + gsum[g] >= (unsigned)KSEL) break;
      acc += gsum[g];
    }
    int t = g * GR;
    for (int bin = g * GR + GR - 1; bin >= g * GR; --bin) {
      acc += ch[bin];
      if (acc >= (unsigned)KSEL) { t = bin; break; }
    }
    tsel[b] = t;
  }
}

// ---------------- 3. compact candidates ----------------
__global__ __launch_bounds__(256) void compact_kernel(const float2* __restrict__ probs,
                                                      const int* __restrict__ tsel,
                                                      int* __restrict__ cnt,
                                                      ull* __restrict__ keys) {
  __shared__ int lcnt, lbase;
  __shared__ ull lbuf[2048];
  int b = blockIdx.y;
  int t = tsel[b];
  if (threadIdx.x == 0) lcnt = 0;
  __syncthreads();
  const float2* p = probs + (size_t)b * NA;
  for (int a = blockIdx.x * blockDim.x + threadIdx.x; a < NA; a += gridDim.x * blockDim.x) {
    float s = p[a].y;
    if (score_bin(s) >= t) {
      int pos = atomicAdd(&lcnt, 1);
      unsigned int ib = ~__float_as_uint(s);
      lbuf[pos] = ((ull)ib << 32) | (unsigned int)a;
    }
  }
  __syncthreads();
  if (threadIdx.x == 0) lbase = atomicAdd(&cnt[b * 16], lcnt);
  __syncthreads();
  int n = lcnt, base = lbase;
  ull* kb = keys + (size_t)b * CAP;
  for (int i = threadIdx.x; i < n; i += 256) {
    int pos = base + i;
    if (pos < CAP) kb[pos] = lbuf[i];
  }
}

// ---------------- 4a. rank by counting ----------------
__global__ __launch_bounds__(256) void rank_kernel(const int* __restrict__ cnt,
                                                   const ull* __restrict__ keys,
                                                   unsigned int* __restrict__ rank) {
  int b = blockIdx.z;
  int n = cnt[b * 16];
  if (n > CAP) n = CAP;
  int i = blockIdx.x * 256 + threadIdx.x;
  if (i >= n) return;
  const ull* kb = keys + (size_t)b * CAP;
  ull my = kb[i];
  int n16 = (n + 15) & ~15;
  int nchunks = n16 >> 4;
  int hc = nchunks >> 1;
  int jlo = (blockIdx.y == 0) ? 0 : hc * 16;
  int jhi = (blockIdx.y == 0) ? hc * 16 : n16;
  unsigned int r = 0;
  for (int j = jlo; j < jhi; j += 16) {
#pragma unroll
    for (int t = 0; t < 16; ++t) {
      r += (kb[j + t] < my) ? 1u : 0u;
    }
  }
  if (r) atomicAdd(&rank[(size_t)b * CAP + i], r);
}

// ---------------- 4b. scatter + box decode ----------------
__global__ __launch_bounds__(256) void scatter_kernel(const float4* __restrict__ anchors4,
                                                      const float4* __restrict__ bbox4,
                                                      const int* __restrict__ cnt,
                                                      const ull* __restrict__ keys,
                                                      const unsigned int* __restrict__ rank,
                                                      float4* __restrict__ boxes4) {
#pragma clang fp contract(off)
  int b = blockIdx.y;
  int n = cnt[b * 16];
  if (n > CAP) n = CAP;
  int i = blockIdx.x * 256 + threadIdx.x;
  if (i >= n) return;
  unsigned int r = rank[(size_t)b * CAP + i];
  if (r >= (unsigned)KSEL) return;
  int a = (int)(unsigned int)(keys[(size_t)b * CAP + i] & 0xffffffffull);
  float4 anc = anchors4[(size_t)b * NA + a];
  float4 d   = bbox4[(size_t)b * NA + a];
  float h = anc.z - anc.x;
  float w = anc.w - anc.y;
  float dy = d.x * 0.1f, dx = d.y * 0.1f, dh = d.z * 0.2f, dw = d.w * 0.2f;
  float cy = (anc.x + (0.5f * h)) + (dy * h);
  float cx = (anc.y + (0.5f * w)) + (dx * w);
  float h2 = h * expf(dh);
  float w2 = w * expf(dw);
  float y1 = cy - 0.5f * h2;
  float x1 = cx - 0.5f * w2;
  float y2 = y1 + h2;
  float x2 = x1 + w2;
  y1 = fminf(fmaxf(y1, 0.f), 1.f);
  x1 = fminf(fmaxf(x1, 0.f), 1.f);
  y2 = fminf(fmaxf(y2, 0.f), 1.f);
  x2 = fminf(fmaxf(x2, 0.f), 1.f);
  boxes4[(size_t)b * KSEL + r] = make_float4(y1, x1, y2, x2);
}

// ---------------- 5. suppression mask, ROW-major [b][row][96] words ----------------
__global__ __launch_bounds__(256) void mask_kernel(const float4* __restrict__ boxes4,
                                                   ull* __restrict__ mask) {
  int cx = blockIdx.x, rb = blockIdx.y, b = blockIdx.z;
  int cb0 = rb + 4 * cx;
  if (cb0 >= NWP) return;
  __shared__ float4 colbox[4][64];
  __shared__ float colca[4][64];
  __shared__ ull wtile[64][5];
  int tid = threadIdx.x, wv = tid >> 6, l = tid & 63;
  int cb = cb0 + wv;
  int row = rb * 64 + l;
  float4 r = (row < KSEL) ? boxes4[(size_t)b * KSEL + row] : make_float4(0.f, 0.f, 0.f, 0.f);
  float ra = (r.z - r.x) * (r.w - r.y);
  int c = cb * 64 + l;
  float4 cload = (cb < NB && c < KSEL) ? boxes4[(size_t)b * KSEL + c]
                                       : make_float4(0.f, 0.f, 0.f, 0.f);
  colbox[wv][l] = cload;
  colca[wv][l] = (cload.z - cload.x) * (cload.w - cload.y);
  __syncthreads();
  ull bits = 0ull;
  if (cb < NB) {
#pragma unroll
    for (int u = 0; u < 64; ++u) {
      float4 cbx = colbox[wv][u];
      float ca = colca[wv][u];
      float ih = fmaxf(fminf(r.z, cbx.z) - fmaxf(r.x, cbx.x), 0.f);
      float iw = fmaxf(fminf(r.w, cbx.w) - fmaxf(r.y, cbx.y), 0.f);
      float inter = ih * iw;
      float s = ra + ca;
      float uni = s - inter;
      float d = fmaf(-0.7f, uni, inter);
      float tt = 6e-7f * uni;
      bool keep;
      if (__builtin_fabsf(d) <= tt) {
        keep = (inter / uni) > 0.7f;
      } else {
        keep = d > 0.f;
      }
      if (keep) bits |= (1ull << u);
    }
    if (cb == rb) {
      bits &= (l == 63) ? 0ull : (~0ull << (l + 1));
    }
  }
  wtile[l][wv] = bits;
  __syncthreads();
  int nrows = min(64, KSEL - rb * 64);
  int rr = tid >> 2, w = tid & 3;
  if (rr < nrows && cb0 + w < NWP)
    mask[((size_t)b * KSEL + (size_t)(rb * 64 + rr)) * NWP + cb0 + w] = wtile[rr][w];
}

// ---------------- 6. single-wave scan: issue-early candidate loads + 2-deep diag pipeline ----------------
// Per block n: A0 = not-yet-suppressed rows (known BEFORE the decision) -> issue their
// row loads at block START (latency hides under the decision); diag gathers ping-pong
// 2 blocks deep with counted vmcnt(1); OR after decision only for kept rows.
__global__ __launch_bounds__(64, 1) void scan_kernel(const float4* __restrict__ boxes4,
                                                     const ull* __restrict__ mask,
                                                     float4* __restrict__ out4) {
  __shared__ int skeep[PROP];
  int b = blockIdx.x;
  int lane = threadIdx.x;
  const ull* mb = mask + (size_t)b * KSEL * NWP;
  int col = (2 * lane < NB) ? 2 * lane : NB;   // lanes >=47 -> pad words 94,95 (zeros)

  ull Sx = 0ull, Sy = 0ull;
  int kept = 0;
  bool done = false;

  u32x4 s0{0,0,0,0}, s1{0,0,0,0}, s2{0,0,0,0}, s3{0,0,0,0},
        s4{0,0,0,0}, s5{0,0,0,0}, s6{0,0,0,0}, s7{0,0,0,0},
        s8{0,0,0,0}, s9{0,0,0,0}, s10{0,0,0,0}, s11{0,0,0,0},
        s12{0,0,0,0}, s13{0,0,0,0}, s14{0,0,0,0}, s15{0,0,0,0},
        s16{0,0,0,0}, s17{0,0,0,0}, s18{0,0,0,0}, s19{0,0,0,0},
        s20{0,0,0,0}, s21{0,0,0,0}, s22{0,0,0,0}, s23{0,0,0,0},
        s24{0,0,0,0}, s25{0,0,0,0}, s26{0,0,0,0}, s27{0,0,0,0},
        s28{0,0,0,0}, s29{0,0,0,0}, s30{0,0,0,0}, s31{0,0,0,0};
  int us[32];
  u32x2 dgA{0,0}, dgB{0,0};

  // prologue: diag gathers for blocks 0 and 1; drain block 0's.
  {
    const void* p0 = (const void*)(mb + (size_t)lane * NWP + 0);
    asm volatile("global_load_dwordx2 %0, %1, off" : "=&v"(dgA) : "v"(p0));
    const void* p1 = (const void*)(mb + (size_t)(64 + lane) * NWP + 1);
    asm volatile("global_load_dwordx2 %0, %1, off" : "=&v"(dgB) : "v"(p1));
    asm volatile("s_waitcnt vmcnt(1)" ::: "memory");
    __builtin_amdgcn_sched_barrier(0);
  }

#define ISSUE1(J, SV) \
    if (J < cnt0) { int u_ = __builtin_ctzll(kk); kk &= (kk - 1ull); us[J] = u_; \
      const void* p_ = (const void*)(mb + (size_t)(i0 + u_) * NWP + col);        \
      asm volatile("global_load_dwordx4 %0, %1, off" : "=&v"(SV) : "v"(p_));     \
    } else us[J] = 0;

#define OR1(J, SV) \
    if (J < cnt0) { if ((K >> us[J]) & 1ull) {    \
      Sx |= ((ull)SV.y << 32) | (ull)SV.x;        \
      Sy |= ((ull)SV.w << 32) | (ull)SV.z; } }

#define NMS_BLOCK(NN, DG)                                                              \
  if (!done) {                                                                         \
    int i0 = (NN) * 64;                                                                \
    int ol = (NN) >> 1;                                                                \
    ull Ssel = ((NN) & 1) ? Sy : Sx;                                                   \
    unsigned slo = (unsigned)__builtin_amdgcn_readlane((int)(unsigned)Ssel, ol);       \
    unsigned shi = (unsigned)__builtin_amdgcn_readlane((int)(unsigned)(Ssel >> 32), ol); \
    ull Sw = (ull)slo | ((ull)shi << 32);                                              \
    int nval = KSEL - i0;                                                              \
    ull valid = (nval >= 64) ? ~0ull : ((1ull << nval) - 1ull);                        \
    ull A0 = ~Sw & valid;                                                              \
    int cnt0 = __builtin_popcountll(A0);                                               \
    ull kk = A0;                                                                       \
    ISSUE1(0, s0)   ISSUE1(1, s1)   ISSUE1(2, s2)   ISSUE1(3, s3)                      \
    ISSUE1(4, s4)   ISSUE1(5, s5)   ISSUE1(6, s6)   ISSUE1(7, s7)                      \
    ISSUE1(8, s8)   ISSUE1(9, s9)   ISSUE1(10, s10) ISSUE1(11, s11)                    \
    ISSUE1(12, s12) ISSUE1(13, s13) ISSUE1(14, s14) ISSUE1(15, s15)                    \
    ISSUE1(16, s16) ISSUE1(17, s17) ISSUE1(18, s18) ISSUE1(19, s19)                    \
    ISSUE1(20, s20) ISSUE1(21, s21) ISSUE1(22, s22) ISSUE1(23, s23)                    \
    ISSUE1(24, s24) ISSUE1(25, s25) ISSUE1(26, s26) ISSUE1(27, s27)                    \
    ISSUE1(28, s28) ISSUE1(29, s29) ISSUE1(30, s30) ISSUE1(31, s31)                    \
    ull kkrem = kk;                                                                    \
    unsigned vlo = (unsigned)DG.x, vhi = (unsigned)DG.y;                               \
    ull A = A0, K = 0ull;                                                              \
    while (A) {                                                                        \
      int u = __builtin_ctzll(A);                                                      \
      if (lane == 0) skeep[kept] = i0 + u;                                             \
      ++kept;                                                                          \
      K |= (1ull << u);                                                                \
      if (kept >= PROP) { done = true; break; }                                        \
      ull Mu = (ull)(unsigned)__builtin_amdgcn_readlane((int)vlo, u)                   \
             | ((ull)(unsigned)__builtin_amdgcn_readlane((int)vhi, u) << 32);          \
      A &= ~(Mu | (1ull << u));                                                        \
    }                                                                                  \
    if (!done) {                                                                       \
      int rn = (NN + 2) * 64 + lane;                                                   \
      if (rn >= KSEL) rn = KSEL - 1;                                                   \
      int wg = ((NN + 2) < NBLK) ? (NN + 2) : (NBLK - 1);                              \
      const void* pg = (const void*)(mb + (size_t)rn * NWP + wg);                      \
      asm volatile("global_load_dwordx2 %0, %1, off" : "=&v"(DG) : "v"(pg));           \
      asm volatile("s_waitcnt vmcnt(1)" ::: "memory");                                 \
      __builtin_amdgcn_sched_barrier(0);                                               \
      OR1(0, s0)   OR1(1, s1)   OR1(2, s2)   OR1(3, s3)                                \
      OR1(4, s4)   OR1(5, s5)   OR1(6, s6)   OR1(7, s7)                                \
      OR1(8, s8)   OR1(9, s9)   OR1(10, s10) OR1(11, s11)                              \
      OR1(12, s12) OR1(13, s13) OR1(14, s14) OR1(15, s15)                              \
      OR1(16, s16) OR1(17, s17) OR1(18, s18) OR1(19, s19)                              \
      OR1(20, s20) OR1(21, s21) OR1(22, s22) OR1(23, s23)                              \
      OR1(24, s24) OR1(25, s25) OR1(26, s26) OR1(27, s27)                              \
      OR1(28, s28) OR1(29, s29) OR1(30, s30) OR1(31, s31)                              \
      ull ke = K & kkrem;                                                              \
      while (ke) {                                                                     \
        int u2 = __builtin_ctzll(ke); ke &= (ke - 1ull);                               \
        u32x4 ex;                                                                      \
        const void* pe = (const void*)(mb + (size_t)(i0 + u2) * NWP + col);            \
        asm volatile("global_load_dwordx4 %0, %1, off" : "=&v"(ex) : "v"(pe));         \
        asm volatile("s_waitcnt vmcnt(0)" ::: "memory");                               \
        __builtin_amdgcn_sched_barrier(0);                                             \
        Sx |= ((ull)ex.y << 32) | (ull)ex.x;                                           \
        Sy |= ((ull)ex.w << 32) | (ull)ex.z;                                           \
      }                                                                                \
    }                                                                                  \
  }

  for (int n = 0; n < NBLK; n += 2) {
    NMS_BLOCK(n, dgA)
    NMS_BLOCK(n + 1, dgB)
    if (done) break;
  }
#undef NMS_BLOCK
#undef ISSUE1
#undef OR1

  asm volatile("s_waitcnt vmcnt(0)" ::: "memory");
  __builtin_amdgcn_sched_barrier(0);

  __syncthreads();
  int fin = kept;
  for (int rr2 = lane; rr2 < PROP; rr2 += 64) {
    float4 v = make_float4(0.f, 0.f, 0.f, 0.f);
    if (rr2 < fin) v = boxes4[(size_t)b * KSEL + skeep[rr2]];
    out4[(size_t)b * PROP + rr2] = v;
  }
}

// ---------------- launch ----------------
extern "C" void kernel_launch(void* const* d_in, const int* in_sizes, int n_in,
                              void* d_out, int out_size, void* d_ws, size_t ws_size,
                              hipStream_t stream) {
  const float2* probs   = (const float2*)d_in[0];
  const float4* bbox4   = (const float4*)d_in[1];
  const float4* anchors4= (const float4*)d_in[2];
  float4* out4 = (float4*)d_out;
  char* ws = (char*)d_ws;

  int* cnt           = (int*)(ws + OFF_CNT);
  int* tsel          = (int*)(ws + OFF_TSEL);
  float4* boxes4     = (float4*)(ws + OFF_BOXES);
  ull* maskw         = (ull*)(ws + OFF_MASK);
  ull* keys          = (ull*)(ws + OFF_KEYS);
  unsigned int* rank = (unsigned int*)(ws + OFF_RANK);
  unsigned int* hist = (unsigned int*)(ws + OFF_HIST);

  hipMemsetAsync(ws + OFF_CNT, 0, 544, stream);
  hipMemsetAsync(ws + OFF_KEYS, 0xFF, 524288, stream);
  hipMemsetAsync(ws + OFF_RANK, 0, 262144, stream);

  hipLaunchKernelGGL(hist_kernel,    dim3(HB, BATCH),     dim3(256), 0, stream, probs, hist);
  hipLaunchKernelGGL(thresh_kernel,  dim3(BATCH),         dim3(256), 0, stream, hist, tsel);
  hipLaunchKernelGGL(compact_kernel, dim3(128, BATCH),    dim3(256), 0, stream, probs, tsel, cnt, keys);
  hipLaunchKernelGGL(rank_kernel,    dim3(32, 2, BATCH),  dim3(256), 0, stream, cnt, keys, rank);
  hipLaunchKernelGGL(scatter_kernel, dim3(32, BATCH),     dim3(256), 0, stream, anchors4, bbox4, cnt, keys, rank, boxes4);
  hipLaunchKernelGGL(mask_kernel,    dim3(24, NB, BATCH), dim3(256), 0, stream, boxes4, maskw);
  hipLaunchKernelGGL(scan_kernel,    dim3(BATCH),         dim3(64),  0, stream, boxes4, maskw, out4);
}

// Round 15
// 471.849 us; speedup vs baseline: 1.1554x; 1.0727x over previous
//
#include <hip/hip_runtime.h>
#include <hip/hip_bf16.h>

typedef unsigned long long ull;
typedef __attribute__((ext_vector_type(4))) unsigned int u32x4;

// ---------------- problem constants ----------------
constexpr int BATCH = 8;
constexpr int NA    = 261888;
constexpr int KSEL  = 6000;          // PRE_NMS_LIMIT
constexpr int PROP  = 1000;          // PROPOSAL_COUNT
constexpr int CAP   = 8192;          // candidate capacity
constexpr int NBINS = 8192;          // histogram bins
constexpr int HB    = 16;            // private histogram blocks per batch
constexpr int NB    = (KSEL + 63) / 64;   // 94 mask words per row
constexpr int NWP   = 94;            // words per row (752B rows, 16B aligned)
constexpr int NBLK  = 94;            // row-blocks
constexpr int NSLOT = 48;            // candidate slots (asm-pinned)

// workspace layout (bytes). keys/rank/hist alias the mask head (disjoint liveness).
constexpr size_t OFF_CNT   = 0;                       // 512
constexpr size_t OFF_TSEL  = 512;                     // 32
constexpr size_t OFF_BOXES = 544;                     // 8*6000*16 = 768000
constexpr size_t OFF_MASK  = 769024;                  // 8*6000*94*8 = 36096000
constexpr size_t OFF_DIAG  = OFF_MASK + 36096000;     // 8*94*64*8 = 385024
constexpr size_t OFF_KEYS  = OFF_MASK;                // aliased
constexpr size_t OFF_RANK  = OFF_MASK + 524288;       // aliased
constexpr size_t OFF_HIST  = OFF_MASK + 2097152;      // aliased
// total = 37,250,048 B (< previously-accepted 37.65MB)

__device__ __forceinline__ int score_bin(float s) {
  int b = (int)(s * (float)NBINS);
  if (b < 0) b = 0;
  if (b > NBINS - 1) b = NBINS - 1;
  return b;
}

// ---------------- 1. histogram ----------------
__global__ __launch_bounds__(256) void hist_kernel(const float2* __restrict__ probs,
                                                   unsigned int* __restrict__ hist) {
  __shared__ unsigned int lh[NBINS];
  for (int i = threadIdx.x; i < NBINS; i += 256) lh[i] = 0u;
  __syncthreads();
  int b = blockIdx.y;
  const float2* p = probs + (size_t)b * NA;
  for (int a = blockIdx.x * 256 + threadIdx.x; a < NA; a += HB * 256) {
    atomicAdd(&lh[score_bin(p[a].y)], 1u);
  }
  __syncthreads();
  unsigned int* gh = hist + ((size_t)b * HB + blockIdx.x) * NBINS;
  for (int i = threadIdx.x; i < NBINS; i += 256) gh[i] = lh[i];
}

// ---------------- 2. threshold bin select ----------------
__global__ __launch_bounds__(256) void thresh_kernel(const unsigned int* __restrict__ hist,
                                                     int* __restrict__ tsel) {
  constexpr int GR = NBINS / 256;
  __shared__ unsigned int ch[NBINS];
  __shared__ unsigned int gsum[256];
  int b = blockIdx.x;
  const unsigned int* h = hist + (size_t)b * HB * NBINS;
  for (int bin = threadIdx.x; bin < NBINS; bin += 256) {
    unsigned int s = 0;
    for (int k = 0; k < HB; ++k) s += h[(size_t)k * NBINS + bin];
    ch[bin] = s;
  }
  __syncthreads();
  unsigned int s = 0;
  int g0 = threadIdx.x * GR;
  for (int i = 0; i < GR; ++i) s += ch[g0 + i];
  gsum[threadIdx.x] = s;
  __syncthreads();
  if (threadIdx.x == 0) {
    unsigned int acc = 0;
    int g = 255;
    for (; g > 0; --g) {
      if (acc + gsum[g] >= (unsigned)KSEL) break;
      acc += gsum[g];
    }
    int t = g * GR;
    for (int bin = g * GR + GR - 1; bin >= g * GR; --bin) {
      acc += ch[bin];
      if (acc >= (unsigned)KSEL) { t = bin; break; }
    }
    tsel[b] = t;
  }
}

// ---------------- 3. compact candidates ----------------
__global__ __launch_bounds__(256) void compact_kernel(const float2* __restrict__ probs,
                                                      const int* __restrict__ tsel,
                                                      int* __restrict__ cnt,
                                                      ull* __restrict__ keys) {
  __shared__ int lcnt, lbase;
  __shared__ ull lbuf[2048];
  int b = blockIdx.y;
  int t = tsel[b];
  if (threadIdx.x == 0) lcnt = 0;
  __syncthreads();
  const float2* p = probs + (size_t)b * NA;
  for (int a = blockIdx.x * blockDim.x + threadIdx.x; a < NA; a += gridDim.x * blockDim.x) {
    float s = p[a].y;
    if (score_bin(s) >= t) {
      int pos = atomicAdd(&lcnt, 1);
      unsigned int ib = ~__float_as_uint(s);
      lbuf[pos] = ((ull)ib << 32) | (unsigned int)a;
    }
  }
  __syncthreads();
  if (threadIdx.x == 0) lbase = atomicAdd(&cnt[b * 16], lcnt);
  __syncthreads();
  int n = lcnt, base = lbase;
  ull* kb = keys + (size_t)b * CAP;
  for (int i = threadIdx.x; i < n; i += 256) {
    int pos = base + i;
    if (pos < CAP) kb[pos] = lbuf[i];
  }
}

// ---------------- 4a. rank by counting ----------------
__global__ __launch_bounds__(256) void rank_kernel(const int* __restrict__ cnt,
                                                   const ull* __restrict__ keys,
                                                   unsigned int* __restrict__ rank) {
  int b = blockIdx.z;
  int n = cnt[b * 16];
  if (n > CAP) n = CAP;
  int i = blockIdx.x * 256 + threadIdx.x;
  if (i >= n) return;
  const ull* kb = keys + (size_t)b * CAP;
  ull my = kb[i];
  int n16 = (n + 15) & ~15;
  int nchunks = n16 >> 4;
  int hc = nchunks >> 1;
  int jlo = (blockIdx.y == 0) ? 0 : hc * 16;
  int jhi = (blockIdx.y == 0) ? hc * 16 : n16;
  unsigned int r = 0;
  for (int j = jlo; j < jhi; j += 16) {
#pragma unroll
    for (int t = 0; t < 16; ++t) {
      r += (kb[j + t] < my) ? 1u : 0u;
    }
  }
  if (r) atomicAdd(&rank[(size_t)b * CAP + i], r);
}

// ---------------- 4b. scatter + box decode ----------------
__global__ __launch_bounds__(256) void scatter_kernel(const float4* __restrict__ anchors4,
                                                      const float4* __restrict__ bbox4,
                                                      const int* __restrict__ cnt,
                                                      const ull* __restrict__ keys,
                                                      const unsigned int* __restrict__ rank,
                                                      float4* __restrict__ boxes4) {
#pragma clang fp contract(off)
  int b = blockIdx.y;
  int n = cnt[b * 16];
  if (n > CAP) n = CAP;
  int i = blockIdx.x * 256 + threadIdx.x;
  if (i >= n) return;
  unsigned int r = rank[(size_t)b * CAP + i];
  if (r >= (unsigned)KSEL) return;
  int a = (int)(unsigned int)(keys[(size_t)b * CAP + i] & 0xffffffffull);
  float4 anc = anchors4[(size_t)b * NA + a];
  float4 d   = bbox4[(size_t)b * NA + a];
  float h = anc.z - anc.x;
  float w = anc.w - anc.y;
  float dy = d.x * 0.1f, dx = d.y * 0.1f, dh = d.z * 0.2f, dw = d.w * 0.2f;
  float cy = (anc.x + (0.5f * h)) + (dy * h);
  float cx = (anc.y + (0.5f * w)) + (dx * w);
  float h2 = h * expf(dh);
  float w2 = w * expf(dw);
  float y1 = cy - 0.5f * h2;
  float x1 = cx - 0.5f * w2;
  float y2 = y1 + h2;
  float x2 = x1 + w2;
  y1 = fminf(fmaxf(y1, 0.f), 1.f);
  x1 = fminf(fmaxf(x1, 0.f), 1.f);
  y2 = fminf(fmaxf(y2, 0.f), 1.f);
  x2 = fminf(fmaxf(x2, 0.f), 1.f);
  boxes4[(size_t)b * KSEL + r] = make_float4(y1, x1, y2, x2);
}

// ---------------- 5. suppression mask, ROW-major [b][row][94] + dense diagT ----------------
__global__ __launch_bounds__(256) void mask_kernel(const float4* __restrict__ boxes4,
                                                   ull* __restrict__ mask,
                                                   ull* __restrict__ diagT) {
  int cx = blockIdx.x, rb = blockIdx.y, b = blockIdx.z;
  int cb0 = rb + 4 * cx;
  if (cb0 >= NWP) return;
  __shared__ float4 colbox[4][64];
  __shared__ float colca[4][64];
  __shared__ ull wtile[64][5];
  int tid = threadIdx.x, wv = tid >> 6, l = tid & 63;
  int cb = cb0 + wv;
  int row = rb * 64 + l;
  float4 r = (row < KSEL) ? boxes4[(size_t)b * KSEL + row] : make_float4(0.f, 0.f, 0.f, 0.f);
  float ra = (r.z - r.x) * (r.w - r.y);
  int c = cb * 64 + l;
  float4 cload = (cb < NB && c < KSEL) ? boxes4[(size_t)b * KSEL + c]
                                       : make_float4(0.f, 0.f, 0.f, 0.f);
  colbox[wv][l] = cload;
  colca[wv][l] = (cload.z - cload.x) * (cload.w - cload.y);
  __syncthreads();
  ull bits = 0ull;
  if (cb < NB) {
#pragma unroll
    for (int u = 0; u < 64; ++u) {
      float4 cbx = colbox[wv][u];
      float ca = colca[wv][u];
      float ih = fmaxf(fminf(r.z, cbx.z) - fmaxf(r.x, cbx.x), 0.f);
      float iw = fmaxf(fminf(r.w, cbx.w) - fmaxf(r.y, cbx.y), 0.f);
      float inter = ih * iw;
      float s = ra + ca;
      float uni = s - inter;
      float d = fmaf(-0.7f, uni, inter);
      float tt = 6e-7f * uni;
      bool keep;
      if (__builtin_fabsf(d) <= tt) {
        keep = (inter / uni) > 0.7f;   // exact tie path (rare; 0/0->NaN->false)
      } else {
        keep = d > 0.f;
      }
      if (keep) bits |= (1ull << u);
    }
    if (cb == rb) {
      bits &= (l == 63) ? 0ull : (~0ull << (l + 1)); // only cc > row suppress
      // dense diagonal word array for scan's decision chain
      diagT[((size_t)b * NBLK + rb) * 64 + l] = bits;
    }
  }
  wtile[l][wv] = bits;
  __syncthreads();
  int nrows = min(64, KSEL - rb * 64);
  int rr = tid >> 2, w = tid & 3;
  if (rr < nrows && cb0 + w < NWP)
    mask[((size_t)b * KSEL + (size_t)(rb * 64 + rr)) * NWP + cb0 + w] = wtile[rr][w];
}

// ---------------- 6. single-wave scan: LDS diag + slot loads with 1-block cover ----------------
// Per block n: [1] vmcnt(0) -> OR kept(n-1) from slots (re-walk A0prev in ctz order),
// [2] compute A0(n), issue 48 asm-pinned slot loads (consumed next block),
// [3] SALU decision using dg (LDS, prefetched 1 block ahead), [4] parallel skeep write.
__global__ __launch_bounds__(64, 1) void scan_kernel(const float4* __restrict__ boxes4,
                                                     const ull* __restrict__ mask,
                                                     const ull* __restrict__ diagT,
                                                     float4* __restrict__ out4) {
  __shared__ ull ldiag[NBLK * 64];   // 48128 B
  __shared__ int skeep[PROP];        // 4000 B
  int b = blockIdx.x;
  int lane = threadIdx.x;
  const ull* mb = mask + (size_t)b * KSEL * NWP;
  int col = (2 * lane <= 92) ? 2 * lane : 92;   // clamp keeps dwordx4 in-row

  // preload dense diag words into LDS (one coalesced sweep)
  const ull* dt = diagT + (size_t)b * NBLK * 64;
  for (int i = lane; i < NBLK * 64; i += 64) ldiag[i] = dt[i];
  __syncthreads();

  ull Sx = 0ull, Sy = 0ull;
  int kept = 0;
  bool done = false;

  u32x4 s0{0,0,0,0}, s1{0,0,0,0}, s2{0,0,0,0}, s3{0,0,0,0},
        s4{0,0,0,0}, s5{0,0,0,0}, s6{0,0,0,0}, s7{0,0,0,0},
        s8{0,0,0,0}, s9{0,0,0,0}, s10{0,0,0,0}, s11{0,0,0,0},
        s12{0,0,0,0}, s13{0,0,0,0}, s14{0,0,0,0}, s15{0,0,0,0},
        s16{0,0,0,0}, s17{0,0,0,0}, s18{0,0,0,0}, s19{0,0,0,0},
        s20{0,0,0,0}, s21{0,0,0,0}, s22{0,0,0,0}, s23{0,0,0,0},
        s24{0,0,0,0}, s25{0,0,0,0}, s26{0,0,0,0}, s27{0,0,0,0},
        s28{0,0,0,0}, s29{0,0,0,0}, s30{0,0,0,0}, s31{0,0,0,0},
        s32{0,0,0,0}, s33{0,0,0,0}, s34{0,0,0,0}, s35{0,0,0,0},
        s36{0,0,0,0}, s37{0,0,0,0}, s38{0,0,0,0}, s39{0,0,0,0},
        s40{0,0,0,0}, s41{0,0,0,0}, s42{0,0,0,0}, s43{0,0,0,0},
        s44{0,0,0,0}, s45{0,0,0,0}, s46{0,0,0,0}, s47{0,0,0,0};

  ull A0prev = 0ull, Kprev = 0ull, kkremA = 0ull;
  int cntA = 0, i0A = 0;

  ull dg = ldiag[lane];              // block 0 diag (per-lane row)

#define ISSUE1(J, SV) \
    if (J < cnt0) { int u_ = __builtin_ctzll(kk); kk &= (kk - 1ull);             \
      const void* p_ = (const void*)(mb + (size_t)(i0 + u_) * NWP + col);        \
      asm volatile("global_load_dwordx4 %0, %1, off" : "=&v"(SV) : "v"(p_));     \
    }
#define OR1(J, SV) \
    if (J < cntA) { int u_ = __builtin_ctzll(kk2); kk2 &= (kk2 - 1ull);          \
      if ((Kprev >> u_) & 1ull) {                                                \
        Sx |= ((ull)SV.y << 32) | (ull)SV.x;                                     \
        Sy |= ((ull)SV.w << 32) | (ull)SV.z; } }

  for (int n = 0; n < NBLK; ++n) {
    int i0 = n * 64;

    // [1] drain previous block's slot loads; OR its kept rows
    asm volatile("s_waitcnt vmcnt(0)" ::: "memory");
    __builtin_amdgcn_sched_barrier(0);
    {
      ull kk2 = A0prev;
      OR1(0, s0)   OR1(1, s1)   OR1(2, s2)   OR1(3, s3)
      OR1(4, s4)   OR1(5, s5)   OR1(6, s6)   OR1(7, s7)
      OR1(8, s8)   OR1(9, s9)   OR1(10, s10) OR1(11, s11)
      OR1(12, s12) OR1(13, s13) OR1(14, s14) OR1(15, s15)
      OR1(16, s16) OR1(17, s17) OR1(18, s18) OR1(19, s19)
      OR1(20, s20) OR1(21, s21) OR1(22, s22) OR1(23, s23)
      OR1(24, s24) OR1(25, s25) OR1(26, s26) OR1(27, s27)
      OR1(28, s28) OR1(29, s29) OR1(30, s30) OR1(31, s31)
      OR1(32, s32) OR1(33, s33) OR1(34, s34) OR1(35, s35)
      OR1(36, s36) OR1(37, s37) OR1(38, s38) OR1(39, s39)
      OR1(40, s40) OR1(41, s41) OR1(42, s42) OR1(43, s43)
      OR1(44, s44) OR1(45, s45) OR1(46, s46) OR1(47, s47)
      // overflow: kept rows beyond the 48 slots (only early blocks)
      ull ke = Kprev & kkremA;
      while (ke) {
        int u2 = __builtin_ctzll(ke); ke &= (ke - 1ull);
        u32x4 ex;
        const void* pe = (const void*)(mb + (size_t)(i0A + u2) * NWP + col);
        asm volatile("global_load_dwordx4 %0, %1, off" : "=&v"(ex) : "v"(pe));
        asm volatile("s_waitcnt vmcnt(0)" ::: "memory");
        __builtin_amdgcn_sched_barrier(0);
        Sx |= ((ull)ex.y << 32) | (ull)ex.x;
        Sy |= ((ull)ex.w << 32) | (ull)ex.z;
      }
    }

    // [2] candidate set for this block; issue slot loads (consumed next block)
    int ol = n >> 1;
    ull Ssel = (n & 1) ? Sy : Sx;
    unsigned slo = (unsigned)__builtin_amdgcn_readlane((int)(unsigned)Ssel, ol);
    unsigned shi = (unsigned)__builtin_amdgcn_readlane((int)(unsigned)(Ssel >> 32), ol);
    ull Sw = (ull)slo | ((ull)shi << 32);
    int nval = KSEL - i0;
    ull valid = (nval >= 64) ? ~0ull : ((1ull << nval) - 1ull);
    ull A0 = ~Sw & valid;
    int cnt0 = __builtin_popcountll(A0);
    ull kk = A0;
    ISSUE1(0, s0)   ISSUE1(1, s1)   ISSUE1(2, s2)   ISSUE1(3, s3)
    ISSUE1(4, s4)   ISSUE1(5, s5)   ISSUE1(6, s6)   ISSUE1(7, s7)
    ISSUE1(8, s8)   ISSUE1(9, s9)   ISSUE1(10, s10) ISSUE1(11, s11)
    ISSUE1(12, s12) ISSUE1(13, s13) ISSUE1(14, s14) ISSUE1(15, s15)
    ISSUE1(16, s16) ISSUE1(17, s17) ISSUE1(18, s18) ISSUE1(19, s19)
    ISSUE1(20, s20) ISSUE1(21, s21) ISSUE1(22, s22) ISSUE1(23, s23)
    ISSUE1(24, s24) ISSUE1(25, s25) ISSUE1(26, s26) ISSUE1(27, s27)
    ISSUE1(28, s28) ISSUE1(29, s29) ISSUE1(30, s30) ISSUE1(31, s31)
    ISSUE1(32, s32) ISSUE1(33, s33) ISSUE1(34, s34) ISSUE1(35, s35)
    ISSUE1(36, s36) ISSUE1(37, s37) ISSUE1(38, s38) ISSUE1(39, s39)
    ISSUE1(40, s40) ISSUE1(41, s41) ISSUE1(42, s42) ISSUE1(43, s43)
    ISSUE1(44, s44) ISSUE1(45, s45) ISSUE1(46, s46) ISSUE1(47, s47)

    // [3] SALU greedy decision using dg (from LDS)
    unsigned vlo = (unsigned)dg, vhi = (unsigned)(dg >> 32);
    ull A = A0, K = 0ull;
    while (A) {
      int u = __builtin_ctzll(A);
      ++kept;
      K |= (1ull << u);
      if (kept >= PROP) { done = true; break; }
      ull Mu = (ull)(unsigned)__builtin_amdgcn_readlane((int)vlo, u)
             | ((ull)(unsigned)__builtin_amdgcn_readlane((int)vhi, u) << 32);
      A &= ~(Mu | (1ull << u));
    }

    // [4] parallel skeep write from K
    {
      int kbase = kept - __builtin_popcountll(K);
      if ((K >> lane) & 1ull) {
        int rank = __builtin_popcountll(K & ((1ull << lane) - 1ull));
        skeep[kbase + rank] = i0 + lane;
      }
    }
    if (done) break;

    // [5] prefetch next block's diag from LDS; save state for next block's OR
    if (n + 1 < NBLK) dg = ldiag[(n + 1) * 64 + lane];
    A0prev = A0; Kprev = K; kkremA = kk; cntA = cnt0; i0A = i0;
  }
#undef ISSUE1
#undef OR1

  asm volatile("s_waitcnt vmcnt(0)" ::: "memory");
  __builtin_amdgcn_sched_barrier(0);

  __syncthreads();
  int fin = kept;
  for (int rr2 = lane; rr2 < PROP; rr2 += 64) {
    float4 v = make_float4(0.f, 0.f, 0.f, 0.f);
    if (rr2 < fin) v = boxes4[(size_t)b * KSEL + skeep[rr2]];
    out4[(size_t)b * PROP + rr2] = v;
  }
}

// ---------------- launch ----------------
extern "C" void kernel_launch(void* const* d_in, const int* in_sizes, int n_in,
                              void* d_out, int out_size, void* d_ws, size_t ws_size,
                              hipStream_t stream) {
  const float2* probs   = (const float2*)d_in[0];
  const float4* bbox4   = (const float4*)d_in[1];
  const float4* anchors4= (const float4*)d_in[2];
  float4* out4 = (float4*)d_out;
  char* ws = (char*)d_ws;

  int* cnt           = (int*)(ws + OFF_CNT);
  int* tsel          = (int*)(ws + OFF_TSEL);
  float4* boxes4     = (float4*)(ws + OFF_BOXES);
  ull* maskw         = (ull*)(ws + OFF_MASK);
  ull* diagT         = (ull*)(ws + OFF_DIAG);
  ull* keys          = (ull*)(ws + OFF_KEYS);
  unsigned int* rank = (unsigned int*)(ws + OFF_RANK);
  unsigned int* hist = (unsigned int*)(ws + OFF_HIST);

  hipMemsetAsync(ws + OFF_CNT, 0, 544, stream);
  hipMemsetAsync(ws + OFF_KEYS, 0xFF, 524288, stream);
  hipMemsetAsync(ws + OFF_RANK, 0, 262144, stream);

  hipLaunchKernelGGL(hist_kernel,    dim3(HB, BATCH),     dim3(256), 0, stream, probs, hist);
  hipLaunchKernelGGL(thresh_kernel,  dim3(BATCH),         dim3(256), 0, stream, hist, tsel);
  hipLaunchKernelGGL(compact_kernel, dim3(128, BATCH),    dim3(256), 0, stream, probs, tsel, cnt, keys);
  hipLaunchKernelGGL(rank_kernel,    dim3(32, 2, BATCH),  dim3(256), 0, stream, cnt, keys, rank);
  hipLaunchKernelGGL(scatter_kernel, dim3(32, BATCH),     dim3(256), 0, stream, anchors4, bbox4, cnt, keys, rank, boxes4);
  hipLaunchKernelGGL(mask_kernel,    dim3(24, NB, BATCH), dim3(256), 0, stream, boxes4, maskw, diagT);
  hipLaunchKernelGGL(scan_kernel,    dim3(BATCH),         dim3(64),  0, stream, boxes4, maskw, diagT, out4);
}

// Round 17
// 372.909 us; speedup vs baseline: 1.4619x; 1.2653x over previous
//
#include <hip/hip_runtime.h>
#include <hip/hip_bf16.h>

typedef unsigned long long ull;

// ---------------- problem constants ----------------
constexpr int BATCH = 8;
constexpr int NA    = 261888;
constexpr int KSEL  = 6000;          // PRE_NMS_LIMIT
constexpr int PROP  = 1000;          // PROPOSAL_COUNT
constexpr int CAP   = 8192;          // candidate capacity
constexpr int NBINS = 8192;          // histogram bins
constexpr int HB    = 16;            // private histogram blocks per batch
constexpr int NB    = (KSEL + 63) / 64;   // 94 mask words per row
constexpr int NWP   = 94;            // words per row (752B rows)
constexpr int NBLK  = 94;            // row-blocks

// workspace layout (bytes). keys/rank/hist alias the mask head (disjoint liveness).
constexpr size_t OFF_CNT   = 0;                       // 512
constexpr size_t OFF_TSEL  = 512;                     // 32
constexpr size_t OFF_BOXES = 544;                     // 8*6000*16 = 768000
constexpr size_t OFF_MASK  = 769024;                  // 8*6000*94*8 = 36096000
constexpr size_t OFF_DIAG  = OFF_MASK + 36096000;     // 8*94*64*8 = 385024
constexpr size_t OFF_KEYS  = OFF_MASK;                // aliased
constexpr size_t OFF_RANK  = OFF_MASK + 524288;       // aliased
constexpr size_t OFF_HIST  = OFF_MASK + 2097152;      // aliased
// total = 37,250,048 B

__device__ __forceinline__ int score_bin(float s) {
  int b = (int)(s * (float)NBINS);
  if (b < 0) b = 0;
  if (b > NBINS - 1) b = NBINS - 1;
  return b;
}

// ---------------- 1. histogram ----------------
__global__ __launch_bounds__(256) void hist_kernel(const float2* __restrict__ probs,
                                                   unsigned int* __restrict__ hist) {
  __shared__ unsigned int lh[NBINS];
  for (int i = threadIdx.x; i < NBINS; i += 256) lh[i] = 0u;
  __syncthreads();
  int b = blockIdx.y;
  const float2* p = probs + (size_t)b * NA;
  for (int a = blockIdx.x * 256 + threadIdx.x; a < NA; a += HB * 256) {
    atomicAdd(&lh[score_bin(p[a].y)], 1u);
  }
  __syncthreads();
  unsigned int* gh = hist + ((size_t)b * HB + blockIdx.x) * NBINS;
  for (int i = threadIdx.x; i < NBINS; i += 256) gh[i] = lh[i];
}

// ---------------- 2. threshold bin select ----------------
__global__ __launch_bounds__(256) void thresh_kernel(const unsigned int* __restrict__ hist,
                                                     int* __restrict__ tsel) {
  constexpr int GR = NBINS / 256;
  __shared__ unsigned int ch[NBINS];
  __shared__ unsigned int gsum[256];
  int b = blockIdx.x;
  const unsigned int* h = hist + (size_t)b * HB * NBINS;
  for (int bin = threadIdx.x; bin < NBINS; bin += 256) {
    unsigned int s = 0;
    for (int k = 0; k < HB; ++k) s += h[(size_t)k * NBINS + bin];
    ch[bin] = s;
  }
  __syncthreads();
  unsigned int s = 0;
  int g0 = threadIdx.x * GR;
  for (int i = 0; i < GR; ++i) s += ch[g0 + i];
  gsum[threadIdx.x] = s;
  __syncthreads();
  if (threadIdx.x == 0) {
    unsigned int acc = 0;
    int g = 255;
    for (; g > 0; --g) {
      if (acc + gsum[g] >= (unsigned)KSEL) break;
      acc += gsum[g];
    }
    int t = g * GR;
    for (int bin = g * GR + GR - 1; bin >= g * GR; --bin) {
      acc += ch[bin];
      if (acc >= (unsigned)KSEL) { t = bin; break; }
    }
    tsel[b] = t;
  }
}

// ---------------- 3. compact candidates ----------------
__global__ __launch_bounds__(256) void compact_kernel(const float2* __restrict__ probs,
                                                      const int* __restrict__ tsel,
                                                      int* __restrict__ cnt,
                                                      ull* __restrict__ keys) {
  __shared__ int lcnt, lbase;
  __shared__ ull lbuf[2048];
  int b = blockIdx.y;
  int t = tsel[b];
  if (threadIdx.x == 0) lcnt = 0;
  __syncthreads();
  const float2* p = probs + (size_t)b * NA;
  for (int a = blockIdx.x * blockDim.x + threadIdx.x; a < NA; a += gridDim.x * blockDim.x) {
    float s = p[a].y;
    if (score_bin(s) >= t) {
      int pos = atomicAdd(&lcnt, 1);
      unsigned int ib = ~__float_as_uint(s);
      lbuf[pos] = ((ull)ib << 32) | (unsigned int)a;
    }
  }
  __syncthreads();
  if (threadIdx.x == 0) lbase = atomicAdd(&cnt[b * 16], lcnt);
  __syncthreads();
  int n = lcnt, base = lbase;
  ull* kb = keys + (size_t)b * CAP;
  for (int i = threadIdx.x; i < n; i += 256) {
    int pos = base + i;
    if (pos < CAP) kb[pos] = lbuf[i];
  }
}

// ---------------- 4a. rank by counting ----------------
__global__ __launch_bounds__(256) void rank_kernel(const int* __restrict__ cnt,
                                                   const ull* __restrict__ keys,
                                                   unsigned int* __restrict__ rank) {
  int b = blockIdx.z;
  int n = cnt[b * 16];
  if (n > CAP) n = CAP;
  int i = blockIdx.x * 256 + threadIdx.x;
  if (i >= n) return;
  const ull* kb = keys + (size_t)b * CAP;
  ull my = kb[i];
  int n16 = (n + 15) & ~15;
  int nchunks = n16 >> 4;
  int hc = nchunks >> 1;
  int jlo = (blockIdx.y == 0) ? 0 : hc * 16;
  int jhi = (blockIdx.y == 0) ? hc * 16 : n16;
  unsigned int r = 0;
  for (int j = jlo; j < jhi; j += 16) {
#pragma unroll
    for (int t = 0; t < 16; ++t) {
      r += (kb[j + t] < my) ? 1u : 0u;
    }
  }
  if (r) atomicAdd(&rank[(size_t)b * CAP + i], r);
}

// ---------------- 4b. scatter + box decode ----------------
__global__ __launch_bounds__(256) void scatter_kernel(const float4* __restrict__ anchors4,
                                                      const float4* __restrict__ bbox4,
                                                      const int* __restrict__ cnt,
                                                      const ull* __restrict__ keys,
                                                      const unsigned int* __restrict__ rank,
                                                      float4* __restrict__ boxes4) {
#pragma clang fp contract(off)
  int b = blockIdx.y;
  int n = cnt[b * 16];
  if (n > CAP) n = CAP;
  int i = blockIdx.x * 256 + threadIdx.x;
  if (i >= n) return;
  unsigned int r = rank[(size_t)b * CAP + i];
  if (r >= (unsigned)KSEL) return;
  int a = (int)(unsigned int)(keys[(size_t)b * CAP + i] & 0xffffffffull);
  float4 anc = anchors4[(size_t)b * NA + a];
  float4 d   = bbox4[(size_t)b * NA + a];
  float h = anc.z - anc.x;
  float w = anc.w - anc.y;
  float dy = d.x * 0.1f, dx = d.y * 0.1f, dh = d.z * 0.2f, dw = d.w * 0.2f;
  float cy = (anc.x + (0.5f * h)) + (dy * h);
  float cx = (anc.y + (0.5f * w)) + (dx * w);
  float h2 = h * expf(dh);
  float w2 = w * expf(dw);
  float y1 = cy - 0.5f * h2;
  float x1 = cx - 0.5f * w2;
  float y2 = y1 + h2;
  float x2 = x1 + w2;
  y1 = fminf(fmaxf(y1, 0.f), 1.f);
  x1 = fminf(fmaxf(x1, 0.f), 1.f);
  y2 = fminf(fmaxf(y2, 0.f), 1.f);
  x2 = fminf(fmaxf(x2, 0.f), 1.f);
  boxes4[(size_t)b * KSEL + r] = make_float4(y1, x1, y2, x2);
}

// ---------------- 5. suppression mask, ROW-major [b][row][94] + dense diagT ----------------
__global__ __launch_bounds__(256) void mask_kernel(const float4* __restrict__ boxes4,
                                                   ull* __restrict__ mask,
                                                   ull* __restrict__ diagT) {
  int cx = blockIdx.x, rb = blockIdx.y, b = blockIdx.z;
  int cb0 = rb + 4 * cx;
  if (cb0 >= NWP) return;
  __shared__ float4 colbox[4][64];
  __shared__ float colca[4][64];
  __shared__ ull wtile[64][5];
  int tid = threadIdx.x, wv = tid >> 6, l = tid & 63;
  int cb = cb0 + wv;
  int row = rb * 64 + l;
  float4 r = (row < KSEL) ? boxes4[(size_t)b * KSEL + row] : make_float4(0.f, 0.f, 0.f, 0.f);
  float ra = (r.z - r.x) * (r.w - r.y);
  int c = cb * 64 + l;
  float4 cload = (cb < NB && c < KSEL) ? boxes4[(size_t)b * KSEL + c]
                                       : make_float4(0.f, 0.f, 0.f, 0.f);
  colbox[wv][l] = cload;
  colca[wv][l] = (cload.z - cload.x) * (cload.w - cload.y);
  __syncthreads();
  ull bits = 0ull;
  if (cb < NB) {
#pragma unroll
    for (int u = 0; u < 64; ++u) {
      float4 cbx = colbox[wv][u];
      float ca = colca[wv][u];
      float ih = fmaxf(fminf(r.z, cbx.z) - fmaxf(r.x, cbx.x), 0.f);
      float iw = fmaxf(fminf(r.w, cbx.w) - fmaxf(r.y, cbx.y), 0.f);
      float inter = ih * iw;
      float s = ra + ca;
      float uni = s - inter;
      float d = fmaf(-0.7f, uni, inter);
      float tt = 6e-7f * uni;
      bool keep;
      if (__builtin_fabsf(d) <= tt) {
        keep = (inter / uni) > 0.7f;   // exact tie path (rare; 0/0->NaN->false)
      } else {
        keep = d > 0.f;
      }
      if (keep) bits |= (1ull << u);
    }
    if (cb == rb) {
      bits &= (l == 63) ? 0ull : (~0ull << (l + 1)); // only cc > row suppress
      diagT[((size_t)b * NBLK + rb) * 64 + l] = bits;
    }
  }
  wtile[l][wv] = bits;
  __syncthreads();
  int nrows = min(64, KSEL - rb * 64);
  int rr = tid >> 2, w = tid & 3;
  if (rr < nrows && cb0 + w < NWP)
    mask[((size_t)b * KSEL + (size_t)(rb * 64 + rr)) * NWP + cb0 + w] = wtile[rr][w];
}

// ---------------- 6. multi-wave scan: lazy column gather + wave-0 SALU decision ----------------
// Per block n: [1] 256 threads gather word n of all kept-so-far rows (4 static guarded
// loads/thread, parallel issue, one wait), [2] barrier, [3] wave 0: 4-partial OR +
// shfl butterfly -> S_n, ctz/readlane greedy with LDS diag, parallel skeep write,
// [4] barrier. No register pipelining across iterations -> nothing to fight hipcc over.
__global__ __launch_bounds__(256, 1) void scan_kernel(const float4* __restrict__ boxes4,
                                                      const ull* __restrict__ mask,
                                                      const ull* __restrict__ diagT,
                                                      float4* __restrict__ out4) {
  __shared__ ull ldiag[NBLK * 64];   // 48128 B
  __shared__ ull sup_part[256];      // 2048 B
  __shared__ int skeep[1024];        // 4096 B (1000 used; padded for safe idx)
  __shared__ int s_kept, s_done;
  int b = blockIdx.x;
  int tid = threadIdx.x;
  int lane = tid & 63;
  const ull* mb = mask + (size_t)b * KSEL * NWP;

  // preload dense diag into LDS (coalesced)
  const ull* dt = diagT + (size_t)b * NBLK * 64;
  for (int i = tid; i < NBLK * 64; i += 256) ldiag[i] = dt[i];
  if (tid == 0) { s_kept = 0; s_done = 0; }
  if (tid < 24) skeep[1000 + tid] = 0;
  __syncthreads();

  for (int n = 0; n < NBLK; ++n) {
    // [1] gather word n of kept rows; 4 independent guarded loads per thread
    int kc = s_kept;
    ull t0 = 0, t1 = 0, t2 = 0, t3 = 0;
    {
      int j0 = tid, j1 = tid + 256, j2 = tid + 512, j3 = tid + 768;
      if (j0 < kc) { int r = skeep[j0]; t0 = mb[(size_t)r * NWP + n]; }
      if (j1 < kc) { int r = skeep[j1]; t1 = mb[(size_t)r * NWP + n]; }
      if (j2 < kc) { int r = skeep[j2]; t2 = mb[(size_t)r * NWP + n]; }
      if (j3 < kc) { int r = skeep[j3]; t3 = mb[(size_t)r * NWP + n]; }
    }
    sup_part[tid] = (t0 | t1) | (t2 | t3);
    __syncthreads();

    // [3] wave 0: reduce + greedy decision
    if (tid < 64) {
      ull p = sup_part[lane] | sup_part[lane + 64] | sup_part[lane + 128] | sup_part[lane + 192];
#pragma unroll
      for (int m = 1; m < 64; m <<= 1) p |= __shfl_xor(p, m, 64);
      ull Sn = p;                              // same in all lanes
      int i0 = n * 64;
      ull dg = ldiag[i0 + lane];
      unsigned vlo = (unsigned)dg, vhi = (unsigned)(dg >> 32);
      int nval = KSEL - i0;
      ull valid = (nval >= 64) ? ~0ull : ((1ull << nval) - 1ull);
      ull A = ~Sn & valid;
      ull K = 0ull;
      int kept = kc;
      int done = 0;
      while (A) {
        int u = __builtin_amdgcn_readfirstlane(__builtin_ctzll(A));
        ++kept;
        K |= (1ull << u);
        if (kept >= PROP) { done = 1; break; }
        ull Mu = (ull)(unsigned)__builtin_amdgcn_readlane((int)vlo, u)
               | ((ull)(unsigned)__builtin_amdgcn_readlane((int)vhi, u) << 32);
        A &= ~(Mu | (1ull << u));
      }
      int kbase = kept - __builtin_popcountll(K);
      if ((K >> lane) & 1ull) {
        int rank = __builtin_popcountll(K & ((1ull << lane) - 1ull));
        skeep[kbase + rank] = i0 + lane;
      }
      if (lane == 0) {
        s_kept = kept;
        if (done || n == NBLK - 1) s_done = 1;
      }
    }
    __syncthreads();
    if (s_done) break;
  }

  int fin = s_kept;
  if (fin > PROP) fin = PROP;
  for (int r2 = tid; r2 < PROP; r2 += 256) {
    float4 v = make_float4(0.f, 0.f, 0.f, 0.f);
    if (r2 < fin) v = boxes4[(size_t)b * KSEL + skeep[r2]];
    out4[(size_t)b * PROP + r2] = v;
  }
}

// ---------------- launch ----------------
extern "C" void kernel_launch(void* const* d_in, const int* in_sizes, int n_in,
                              void* d_out, int out_size, void* d_ws, size_t ws_size,
                              hipStream_t stream) {
  const float2* probs   = (const float2*)d_in[0];
  const float4* bbox4   = (const float4*)d_in[1];
  const float4* anchors4= (const float4*)d_in[2];
  float4* out4 = (float4*)d_out;
  char* ws = (char*)d_ws;

  int* cnt           = (int*)(ws + OFF_CNT);
  int* tsel          = (int*)(ws + OFF_TSEL);
  float4* boxes4     = (float4*)(ws + OFF_BOXES);
  ull* maskw         = (ull*)(ws + OFF_MASK);
  ull* diagT         = (ull*)(ws + OFF_DIAG);
  ull* keys          = (ull*)(ws + OFF_KEYS);
  unsigned int* rank = (unsigned int*)(ws + OFF_RANK);
  unsigned int* hist = (unsigned int*)(ws + OFF_HIST);

  hipMemsetAsync(ws + OFF_CNT, 0, 544, stream);
  hipMemsetAsync(ws + OFF_KEYS, 0xFF, 524288, stream);
  hipMemsetAsync(ws + OFF_RANK, 0, 262144, stream);

  hipLaunchKernelGGL(hist_kernel,    dim3(HB, BATCH),     dim3(256), 0, stream, probs, hist);
  hipLaunchKernelGGL(thresh_kernel,  dim3(BATCH),         dim3(256), 0, stream, hist, tsel);
  hipLaunchKernelGGL(compact_kernel, dim3(128, BATCH),    dim3(256), 0, stream, probs, tsel, cnt, keys);
  hipLaunchKernelGGL(rank_kernel,    dim3(32, 2, BATCH),  dim3(256), 0, stream, cnt, keys, rank);
  hipLaunchKernelGGL(scatter_kernel, dim3(32, BATCH),     dim3(256), 0, stream, anchors4, bbox4, cnt, keys, rank, boxes4);
  hipLaunchKernelGGL(mask_kernel,    dim3(24, NB, BATCH), dim3(256), 0, stream, boxes4, maskw, diagT);
  hipLaunchKernelGGL(scan_kernel,    dim3(BATCH),         dim3(256), 0, stream, boxes4, maskw, diagT, out4);
}